// Round 6
// baseline (1252.700 us; speedup 1.0000x reference)
//
#include <hip/hip_runtime.h>
#include <hip/hip_fp16.h>

#define N_NODES 50000
#define N_EDGES 800000
#define HD 128
#define NLAYERS 5
#define EINC 16
#define NG 512

typedef _Float16 half8 __attribute__((ext_vector_type(8)));
typedef float f32x4 __attribute__((ext_vector_type(4)));
typedef float f32x2 __attribute__((ext_vector_type(2)));

// ---------------- embedding ----------------
__global__ __launch_bounds__(256) void k_embed(const int* __restrict__ x,
                                               const float* __restrict__ emb,
                                               float* __restrict__ h) {
  int i = blockIdx.x * 256 + threadIdx.x;
  if (i < N_NODES * 32) {
    int n = i >> 5, cv = i & 31;
    *(float4*)&h[n * HD + cv * 4] = *(const float4*)&emb[x[n] * HD + cv * 4];
  }
}

// ---------------- CSR build ----------------
__global__ __launch_bounds__(256) void k_hist(const int* __restrict__ ei,
                                              int* __restrict__ deg) {
  int e = blockIdx.x * 256 + threadIdx.x;
  if (e < N_EDGES) atomicAdd(&deg[ei[N_EDGES + e]], 1);
}

__global__ __launch_bounds__(256) void k_scan1(const int* __restrict__ deg,
                                               int* __restrict__ incl,
                                               int* __restrict__ bsum) {
  __shared__ int s[256];
  int i = blockIdx.x * 256 + threadIdx.x;
  int v = (i < N_NODES) ? deg[i] : 0;
  s[threadIdx.x] = v;
  __syncthreads();
  for (int d = 1; d < 256; d <<= 1) {
    int t = (threadIdx.x >= d) ? s[threadIdx.x - d] : 0;
    __syncthreads();
    s[threadIdx.x] += t;
    __syncthreads();
  }
  if (i < N_NODES) incl[i] = s[threadIdx.x];
  if (threadIdx.x == 255) bsum[blockIdx.x] = s[255];
}

__global__ void k_scan2(int* __restrict__ bsum, int nb) {
  __shared__ int s[256];
  int v = (threadIdx.x < nb) ? bsum[threadIdx.x] : 0;
  s[threadIdx.x] = v;
  __syncthreads();
  for (int d = 1; d < 256; d <<= 1) {
    int t = (threadIdx.x >= d) ? s[threadIdx.x - d] : 0;
    __syncthreads();
    s[threadIdx.x] += t;
    __syncthreads();
  }
  if (threadIdx.x < nb) bsum[threadIdx.x] = s[threadIdx.x];
}

__global__ __launch_bounds__(256) void k_scan3(const int* __restrict__ deg,
                                               const int* __restrict__ incl,
                                               const int* __restrict__ bsum,
                                               int* __restrict__ offs,
                                               int* __restrict__ cursor) {
  int i = blockIdx.x * 256 + threadIdx.x;
  if (i < N_NODES) {
    int base = (blockIdx.x > 0) ? bsum[blockIdx.x - 1] : 0;
    int start = base + incl[i] - deg[i];
    offs[i] = start;
    cursor[i] = start;
    if (i == N_NODES - 1) offs[N_NODES] = N_EDGES;
  }
}

__global__ __launch_bounds__(256) void k_scatter(const int* __restrict__ ei,
                                                 const float* __restrict__ ea,
                                                 int* __restrict__ cursor,
                                                 int* __restrict__ srcs,
                                                 int* __restrict__ eids,
                                                 float* __restrict__ ea_s,
                                                 int permuted) {
  int e = blockIdx.x * 256 + threadIdx.x;
  if (e < N_EDGES) {
    int dst = ei[N_EDGES + e];
    int pos = atomicAdd(&cursor[dst], 1);
    srcs[pos] = ei[e];
    eids[pos] = e;
    if (permuted) {
      float4 a0 = *(const float4*)&ea[(size_t)e * EINC];
      float4 a1 = *(const float4*)&ea[(size_t)e * EINC + 4];
      float4 a2 = *(const float4*)&ea[(size_t)e * EINC + 8];
      float4 a3 = *(const float4*)&ea[(size_t)e * EINC + 12];
      *(float4*)&ea_s[(size_t)pos * EINC] = a0;
      *(float4*)&ea_s[(size_t)pos * EINC + 4] = a1;
      *(float4*)&ea_s[(size_t)pos * EINC + 8] = a2;
      *(float4*)&ea_s[(size_t)pos * EINC + 12] = a3;
    }
  }
}

// ---------------- weight convert+transpose to fp16 (once per launch) ----------------
__global__ __launch_bounds__(256) void k_cvtw1(const float* __restrict__ W1,
                                               _Float16* __restrict__ w1t) {
  int i = blockIdx.x * 256 + threadIdx.x;
  if (i < NLAYERS * 256 * 128) {
    int l = i >> 15, r = i & 32767;
    int n = r >> 7, k = r & 127;
    w1t[i] = (_Float16)W1[(size_t)l * 32768 + k * 256 + n];
  }
}
__global__ __launch_bounds__(256) void k_cvtw2(const float* __restrict__ W2,
                                               _Float16* __restrict__ w2t) {
  int i = blockIdx.x * 256 + threadIdx.x;
  if (i < NLAYERS * 128 * 256) {
    int l = i >> 15, r = i & 32767;
    int n = r >> 8, k = r & 255;
    w2t[i] = (_Float16)W2[(size_t)l * 32768 + k * 128 + n];
  }
}

// -------- fused per-node aggregation: z = (1+eps)h + sum_in relu(h[src]+e) --------
// one wave per node; lane covers channels (2*lane, 2*lane+1).
// edge-MLP as k-paired packed FMA: ea k-pair (SGPR pair) x W k-pair (VGPR pair).
__global__ __launch_bounds__(256) void k_aggr(const int* __restrict__ offs,
                                              const int* __restrict__ srcs,
                                              const int* __restrict__ eids,
                                              const float* __restrict__ ea,
                                              const float* __restrict__ ea_s,
                                              const float* __restrict__ W,   // [16][128]
                                              const float* __restrict__ eb,  // [128]
                                              const float* __restrict__ epsA, int layer,
                                              const float* __restrict__ h,
                                              float* __restrict__ z,
                                              int permuted) {
  const int wid = threadIdx.x >> 6;
  const int lane = threadIdx.x & 63;
  int n = blockIdx.x * 4 + wid;
  if (n >= N_NODES) return;
  const int c0 = lane * 2;

  // k-paired weights for my two channels: wA[i]={W[2i][c0],W[2i+1][c0]}, wB likewise for c0+1
  f32x2 wA[8], wB[8];
#pragma unroll
  for (int i = 0; i < 8; ++i) {
    f32x2 r0 = *(const f32x2*)&W[(2 * i) * HD + c0];
    f32x2 r1 = *(const f32x2*)&W[(2 * i + 1) * HD + c0];
    wA[i][0] = r0[0]; wA[i][1] = r1[0];
    wB[i][0] = r0[1]; wB[i][1] = r1[1];
  }
  const float ebA = eb[c0], ebB = eb[c0 + 1];
  const float epsv = 1.0f + epsA[layer];

  int j0 = offs[n], j1 = offs[n + 1];
  f32x2 hs = *(const f32x2*)&h[(size_t)n * HD + c0];
  float acc0 = epsv * hs[0];
  float acc1 = epsv * hs[1];

  if (permuted) {
#pragma unroll 2
    for (int j = j0; j < j1; ++j) {
      int js = __builtin_amdgcn_readfirstlane(j);
      const float* ra = &ea_s[(size_t)js * EINC];
      int src = __builtin_amdgcn_readfirstlane(srcs[js]);
      f32x2 h2 = *(const f32x2*)&h[(size_t)src * HD + c0];
      f32x2 eA = {ebA, 0.f};
      f32x2 eB = {ebB, 0.f};
#pragma unroll
      for (int i = 0; i < 8; ++i) {
        f32x2 a2 = *(const f32x2*)&ra[2 * i];   // wave-uniform (SGPR pair)
        eA = __builtin_elementwise_fma(a2, wA[i], eA);
        eB = __builtin_elementwise_fma(a2, wB[i], eB);
      }
      acc0 += fmaxf(h2[0] + eA[0] + eA[1], 0.0f);
      acc1 += fmaxf(h2[1] + eB[0] + eB[1], 0.0f);
    }
  } else {
#pragma unroll 2
    for (int j = j0; j < j1; ++j) {
      int js = __builtin_amdgcn_readfirstlane(j);
      int eid = __builtin_amdgcn_readfirstlane(eids[js]);
      const float* ra = &ea[(size_t)eid * EINC];
      int src = __builtin_amdgcn_readfirstlane(srcs[js]);
      f32x2 h2 = *(const f32x2*)&h[(size_t)src * HD + c0];
      f32x2 eA = {ebA, 0.f};
      f32x2 eB = {ebB, 0.f};
#pragma unroll
      for (int i = 0; i < 8; ++i) {
        f32x2 a2 = *(const f32x2*)&ra[2 * i];
        eA = __builtin_elementwise_fma(a2, wA[i], eA);
        eB = __builtin_elementwise_fma(a2, wB[i], eB);
      }
      acc0 += fmaxf(h2[0] + eA[0] + eA[1], 0.0f);
      acc1 += fmaxf(h2[1] + eB[0] + eB[1], 0.0f);
    }
  }
  f32x2 o; o[0] = acc0; o[1] = acc1;
  *(f32x2*)&z[(size_t)n * HD + c0] = o;
}

// ---------- GEMM1 (MFMA fp16): y1h = fp16(z @ W1 + b1) ; col stats ----------
__global__ __launch_bounds__(256) void k_gemm1m(const float* __restrict__ z,
                                                const _Float16* __restrict__ w1t, // [256][128]
                                                const float* __restrict__ bias,   // [256]
                                                _Float16* __restrict__ y1h,
                                                float* __restrict__ gsum,
                                                float* __restrict__ gsq) {
  __shared__ _Float16 sA[128 * 40];
  __shared__ _Float16 sBT[128 * 40];
  __shared__ float ssum[128], ssq[128];
  const int tid = threadIdx.x;
  const int lane = tid & 63;
  const int wid = tid >> 6;
  const int wm = wid >> 1, wn = wid & 1;
  const int m0 = blockIdx.x * 128;
  const int n0 = blockIdx.y * 128;

  if (tid < 128) { ssum[tid] = 0.f; ssq[tid] = 0.f; }

  f32x4 acc[4][4];
  const f32x4 zz = {0.f, 0.f, 0.f, 0.f};
#pragma unroll
  for (int a = 0; a < 4; ++a)
#pragma unroll
    for (int b = 0; b < 4; ++b) acc[a][b] = zz;

  const int srow = tid >> 1;
  const int skh = (tid & 1) * 16;

  for (int k0 = 0; k0 < 128; k0 += 32) {
    {
      int n = m0 + srow;
      half8 p0, p1;
      if (n < N_NODES) {
        float4 a0 = *(const float4*)&z[(size_t)n * 128 + k0 + skh + 0];
        float4 a1 = *(const float4*)&z[(size_t)n * 128 + k0 + skh + 4];
        float4 a2 = *(const float4*)&z[(size_t)n * 128 + k0 + skh + 8];
        float4 a3 = *(const float4*)&z[(size_t)n * 128 + k0 + skh + 12];
        p0[0] = (_Float16)a0.x; p0[1] = (_Float16)a0.y; p0[2] = (_Float16)a0.z; p0[3] = (_Float16)a0.w;
        p0[4] = (_Float16)a1.x; p0[5] = (_Float16)a1.y; p0[6] = (_Float16)a1.z; p0[7] = (_Float16)a1.w;
        p1[0] = (_Float16)a2.x; p1[1] = (_Float16)a2.y; p1[2] = (_Float16)a2.z; p1[3] = (_Float16)a2.w;
        p1[4] = (_Float16)a3.x; p1[5] = (_Float16)a3.y; p1[6] = (_Float16)a3.z; p1[7] = (_Float16)a3.w;
      } else {
#pragma unroll
        for (int j = 0; j < 8; ++j) { p0[j] = (_Float16)0.f; p1[j] = (_Float16)0.f; }
      }
      *(half8*)&sA[srow * 40 + skh] = p0;
      *(half8*)&sA[srow * 40 + skh + 8] = p1;
    }
    {
      half8 u0 = *(const half8*)&w1t[(size_t)(n0 + srow) * 128 + k0 + skh];
      half8 u1 = *(const half8*)&w1t[(size_t)(n0 + srow) * 128 + k0 + skh + 8];
      *(half8*)&sBT[srow * 40 + skh] = u0;
      *(half8*)&sBT[srow * 40 + skh + 8] = u1;
    }
    __syncthreads();
    half8 af[4], bf[4];
#pragma unroll
    for (int t = 0; t < 4; ++t) {
      af[t] = *(const half8*)&sA[(wm * 64 + t * 16 + (lane & 15)) * 40 + (lane >> 4) * 8];
      bf[t] = *(const half8*)&sBT[(wn * 64 + t * 16 + (lane & 15)) * 40 + (lane >> 4) * 8];
    }
#pragma unroll
    for (int tm = 0; tm < 4; ++tm)
#pragma unroll
      for (int tn = 0; tn < 4; ++tn)
        acc[tm][tn] = __builtin_amdgcn_mfma_f32_16x16x32_f16(af[tm], bf[tn], acc[tm][tn], 0, 0, 0);
    __syncthreads();
  }

  float bsv[4];
#pragma unroll
  for (int tn = 0; tn < 4; ++tn) bsv[tn] = bias[n0 + wn * 64 + tn * 16 + (lane & 15)];
  float sacc[4] = {0.f, 0.f, 0.f, 0.f}, qacc[4] = {0.f, 0.f, 0.f, 0.f};
#pragma unroll
  for (int tm = 0; tm < 4; ++tm) {
    int nbase = m0 + wm * 64 + tm * 16 + (lane >> 4) * 4;
#pragma unroll
    for (int r = 0; r < 4; ++r) {
      int n = nbase + r;
      if (n < N_NODES) {
#pragma unroll
        for (int tn = 0; tn < 4; ++tn) {
          float v = acc[tm][tn][r] + bsv[tn];
          y1h[(size_t)n * 256 + n0 + wn * 64 + tn * 16 + (lane & 15)] = (_Float16)v;
          sacc[tn] += v; qacc[tn] += v * v;
        }
      }
    }
  }
#pragma unroll
  for (int tn = 0; tn < 4; ++tn) {
    int c = wn * 64 + tn * 16 + (lane & 15);
    atomicAdd(&ssum[c], sacc[tn]);
    atomicAdd(&ssq[c], qacc[tn]);
  }
  __syncthreads();
  if (tid < 128) {
    unsafeAtomicAdd(&gsum[n0 + tid], ssum[tid]);
    unsafeAtomicAdd(&gsq[n0 + tid], ssq[tid]);
  }
}

// ---------- GEMM2 (MFMA fp16): y2 = relu(bn1(y1h)) @ W2 + b2 ; col stats ----------
__global__ __launch_bounds__(256) void k_gemm2m(const _Float16* __restrict__ y1h,
                                                const float* __restrict__ sc,
                                                const float* __restrict__ sh,
                                                const _Float16* __restrict__ w2t, // [128][256]
                                                const float* __restrict__ bias,   // [128]
                                                float* __restrict__ y2,
                                                float* __restrict__ gsum,
                                                float* __restrict__ gsq) {
  __shared__ _Float16 sA[64 * 40];
  __shared__ _Float16 sBT[128 * 40];
  __shared__ float ssc[256], ssh[256];
  __shared__ float ssum[128], ssq[128];
  const int tid = threadIdx.x;
  const int lane = tid & 63;
  const int wid = tid >> 6;
  const int wm = wid >> 1, wn = wid & 1;
  const int m0 = blockIdx.x * 64;

  ssc[tid] = sc[tid];
  ssh[tid] = sh[tid];
  if (tid < 128) { ssum[tid] = 0.f; ssq[tid] = 0.f; }
  __syncthreads();

  f32x4 acc[2][4];
  const f32x4 zz = {0.f, 0.f, 0.f, 0.f};
#pragma unroll
  for (int a = 0; a < 2; ++a)
#pragma unroll
    for (int b = 0; b < 4; ++b) acc[a][b] = zz;

  const int arow = tid >> 2;
  const int akq = (tid & 3) * 8;
  const int brow = tid >> 1;
  const int bkh = (tid & 1) * 16;

  for (int k0 = 0; k0 < 256; k0 += 32) {
    {
      int n = m0 + arow;
      half8 p;
      if (n < N_NODES) {
        half8 yv = *(const half8*)&y1h[(size_t)n * 256 + k0 + akq];
#pragma unroll
        for (int j = 0; j < 8; ++j) {
          float v = fmaxf((float)yv[j] * ssc[k0 + akq + j] + ssh[k0 + akq + j], 0.f);
          p[j] = (_Float16)v;
        }
      } else {
#pragma unroll
        for (int j = 0; j < 8; ++j) p[j] = (_Float16)0.f;
      }
      *(half8*)&sA[arow * 40 + akq] = p;
    }
    {
      half8 u0 = *(const half8*)&w2t[(size_t)brow * 256 + k0 + bkh];
      half8 u1 = *(const half8*)&w2t[(size_t)brow * 256 + k0 + bkh + 8];
      *(half8*)&sBT[brow * 40 + bkh] = u0;
      *(half8*)&sBT[brow * 40 + bkh + 8] = u1;
    }
    __syncthreads();
    half8 af[2], bf[4];
#pragma unroll
    for (int t = 0; t < 2; ++t)
      af[t] = *(const half8*)&sA[(wm * 32 + t * 16 + (lane & 15)) * 40 + (lane >> 4) * 8];
#pragma unroll
    for (int t = 0; t < 4; ++t)
      bf[t] = *(const half8*)&sBT[(wn * 64 + t * 16 + (lane & 15)) * 40 + (lane >> 4) * 8];
#pragma unroll
    for (int tm = 0; tm < 2; ++tm)
#pragma unroll
      for (int tn = 0; tn < 4; ++tn)
        acc[tm][tn] = __builtin_amdgcn_mfma_f32_16x16x32_f16(af[tm], bf[tn], acc[tm][tn], 0, 0, 0);
    __syncthreads();
  }

  float bsv[4];
#pragma unroll
  for (int tn = 0; tn < 4; ++tn) bsv[tn] = bias[wn * 64 + tn * 16 + (lane & 15)];
  float sacc[4] = {0.f, 0.f, 0.f, 0.f}, qacc[4] = {0.f, 0.f, 0.f, 0.f};
#pragma unroll
  for (int tm = 0; tm < 2; ++tm) {
    int nbase = m0 + wm * 32 + tm * 16 + (lane >> 4) * 4;
#pragma unroll
    for (int r = 0; r < 4; ++r) {
      int n = nbase + r;
      if (n < N_NODES) {
#pragma unroll
        for (int tn = 0; tn < 4; ++tn) {
          float v = acc[tm][tn][r] + bsv[tn];
          y2[(size_t)n * 128 + wn * 64 + tn * 16 + (lane & 15)] = v;
          sacc[tn] += v; qacc[tn] += v * v;
        }
      }
    }
  }
#pragma unroll
  for (int tn = 0; tn < 4; ++tn) {
    int c = wn * 64 + tn * 16 + (lane & 15);
    atomicAdd(&ssum[c], sacc[tn]);
    atomicAdd(&ssq[c], qacc[tn]);
  }
  __syncthreads();
  if (tid < 128) {
    unsafeAtomicAdd(&gsum[tid], ssum[tid]);
    unsafeAtomicAdd(&gsq[tid], ssq[tid]);
  }
}

// ---------------- BN finalize ----------------
__global__ void k_bnfin(const float* __restrict__ sum, const float* __restrict__ sq,
                        const float* __restrict__ g, const float* __restrict__ b,
                        float* __restrict__ sc, float* __restrict__ sh, int C) {
  int c = blockIdx.x * blockDim.x + threadIdx.x;
  if (c < C) {
    const float invN = 1.0f / (float)N_NODES;
    float m = sum[c] * invN;
    float v = fmaxf(sq[c] * invN - m * m, 0.0f);
    float rs = rsqrtf(v + 1e-5f);
    float scale = g[c] * rs;
    sc[c] = scale;
    sh[c] = b[c] - m * scale;
  }
}

// ---------------- apply BN (+optional relu) ----------------
__global__ __launch_bounds__(256) void k_bnapply(const float* __restrict__ y2,
                                                 const float* __restrict__ sc,
                                                 const float* __restrict__ sh,
                                                 float* __restrict__ h, int dorelu) {
  int i = blockIdx.x * 256 + threadIdx.x;
  if (i < N_NODES * 32) {
    int cv = i & 31;
    float4 v = *(const float4*)&y2[i * 4];
    float4 s4 = *(const float4*)&sc[cv * 4];
    float4 h4 = *(const float4*)&sh[cv * 4];
    float4 o;
    o.x = v.x * s4.x + h4.x; o.y = v.y * s4.y + h4.y;
    o.z = v.z * s4.z + h4.z; o.w = v.w * s4.w + h4.w;
    if (dorelu) {
      o.x = fmaxf(o.x, 0.f); o.y = fmaxf(o.y, 0.f);
      o.z = fmaxf(o.z, 0.f); o.w = fmaxf(o.w, 0.f);
    }
    *(float4*)&h[i * 4] = o;
  }
}

// ---------------- pooling: sorted-batch segment reduction ----------------
__global__ void k_goff(const int* __restrict__ batch, int* __restrict__ goff) {
  int g = blockIdx.x * blockDim.x + threadIdx.x;
  if (g <= NG) {
    if (g == NG) { goff[g] = N_NODES; return; }
    int lo = 0, hi = N_NODES;
    while (lo < hi) { int mid = (lo + hi) >> 1; if (batch[mid] < g) lo = mid + 1; else hi = mid; }
    goff[g] = lo;
  }
}

__global__ __launch_bounds__(256) void k_poolseg(const float* __restrict__ h,
                                                 const int* __restrict__ goff,
                                                 float* __restrict__ pooled) {
  __shared__ float sred[256];
  int g = blockIdx.x;
  int c = threadIdx.x & 127;
  int half = threadIdx.x >> 7;
  int n0 = goff[g], n1 = goff[g + 1];
  float s = 0.f;
  for (int n = n0 + half; n < n1; n += 2) s += h[(size_t)n * HD + c];
  sred[threadIdx.x] = s;
  __syncthreads();
  if (threadIdx.x < 128) {
    float tot = sred[threadIdx.x] + sred[threadIdx.x + 128];
    float cntf = (float)(n1 - n0);
    pooled[g * HD + threadIdx.x] = tot / fmaxf(cntf, 1.0f);
  }
}

// ---------------- final GEMM ----------------
__global__ __launch_bounds__(128) void k_final(const float* __restrict__ pooled,
                                               const float* __restrict__ oW,
                                               const float* __restrict__ ob,
                                               float* __restrict__ out) {
  __shared__ float sP[HD];
  int g = blockIdx.x;
  int c = threadIdx.x;
  sP[c] = pooled[g * HD + c];
  __syncthreads();
  float acc = ob[c];
#pragma unroll 8
  for (int k = 0; k < HD; ++k) acc += sP[k] * oW[k * HD + c];
  out[g * HD + c] = acc;
}

extern "C" void kernel_launch(void* const* d_in, const int* in_sizes, int n_in,
                              void* d_out, int out_size, void* d_ws, size_t ws_size,
                              hipStream_t stream) {
  const int* x = (const int*)d_in[0];
  const int* ei = (const int*)d_in[1];
  const float* ea = (const float*)d_in[2];
  const int* batch = (const int*)d_in[3];
  const float* emb = (const float*)d_in[4];
  const float* eW = (const float*)d_in[5];
  const float* eb = (const float*)d_in[6];
  const float* epsA = (const float*)d_in[7];
  const float* W1 = (const float*)d_in[8];
  const float* b1 = (const float*)d_in[9];
  const float* g1 = (const float*)d_in[10];
  const float* be1 = (const float*)d_in[11];
  const float* W2 = (const float*)d_in[12];
  const float* b2 = (const float*)d_in[13];
  const float* bng = (const float*)d_in[14];
  const float* bnb = (const float*)d_in[15];
  const float* oW = (const float*)d_in[16];
  const float* ob = (const float*)d_in[17];
  float* out = (float*)d_out;

  // ----- workspace layout: ints first, then floats -----
  int* ip = (int*)d_ws;
  int* deg = ip;                         // 50,000
  int* incl = deg + 50000;               // 50,000
  int* offs = incl + 50000;              // 50,001
  int* cursor = offs + 50001;            // 50,000
  int* srcs = cursor + 50000;            // 800,000
  int* eids = srcs + 800000;             // 800,000
  int* bsum = eids + 800000;             // 200
  int* goff = bsum + 200;                // 513
  float* fp = (float*)(ip + 1800916);
  float* h = fp;                         // 6,400,000
  float* zbuf = h + 6400000;             // 6,400,000 (z and y2 alias)
  _Float16* y1h = (_Float16*)(zbuf + 6400000);  // 12,800,000 halves
  float* stats = zbuf + 12800000;        // 768
  float* sc1 = stats + 768;              // 256
  float* sh1 = sc1 + 256;                // 256
  float* sc2 = sh1 + 256;                // 128
  float* sh2 = sc2 + 128;                // 128
  float* pooled = sh2 + 128;             // 65,536
  _Float16* w1t = (_Float16*)(pooled + 65536);  // 163,840 halves
  _Float16* w2t = w1t + 163840;                 // 163,840 halves
  float* ea_s = pooled + 65536 + 163840;        // 12,800,000 (optional)

  size_t needed_with = (size_t)(ea_s + 12800000 - (float*)d_ws) * 4;
  int permuted = (ws_size >= needed_with) ? 1 : 0;

  const int vec_blocks = (N_NODES * 32 + 255) / 256;
  const int edge_blocks = (N_EDGES + 255) / 256;
  const int node_blocks = (N_NODES + 255) / 256;

  k_embed<<<vec_blocks, 256, 0, stream>>>(x, emb, h);

  // CSR build + weight conversion (once per launch)
  hipMemsetAsync(deg, 0, 50000 * sizeof(int), stream);
  k_hist<<<edge_blocks, 256, 0, stream>>>(ei, deg);
  k_scan1<<<node_blocks, 256, 0, stream>>>(deg, incl, bsum);
  k_scan2<<<1, 256, 0, stream>>>(bsum, node_blocks);
  k_scan3<<<node_blocks, 256, 0, stream>>>(deg, incl, bsum, offs, cursor);
  k_scatter<<<edge_blocks, 256, 0, stream>>>(ei, ea, cursor, srcs, eids, ea_s, permuted);
  k_goff<<<3, 256, 0, stream>>>(batch, goff);
  k_cvtw1<<<640, 256, 0, stream>>>(W1, w1t);
  k_cvtw2<<<640, 256, 0, stream>>>(W2, w2t);

  for (int l = 0; l < NLAYERS; ++l) {
    hipMemsetAsync(stats, 0, 768 * sizeof(float), stream);
    k_aggr<<<(N_NODES + 3) / 4, 256, 0, stream>>>(offs, srcs, eids, ea, ea_s,
                                                  eW + (size_t)l * EINC * HD, eb + l * HD,
                                                  epsA, l, h, zbuf, permuted);
    k_gemm1m<<<dim3(391, 2), 256, 0, stream>>>(zbuf, w1t + (size_t)l * 32768,
                                               b1 + l * 256, y1h, stats, stats + 256);
    k_bnfin<<<1, 256, 0, stream>>>(stats, stats + 256, g1 + l * 256, be1 + l * 256, sc1, sh1, 256);
    k_gemm2m<<<782, 256, 0, stream>>>(y1h, sc1, sh1, w2t + (size_t)l * 32768,
                                      b2 + l * HD, zbuf, stats + 512, stats + 640);
    k_bnfin<<<1, 128, 0, stream>>>(stats + 512, stats + 640, bng + l * HD, bnb + l * HD, sc2, sh2, 128);
    k_bnapply<<<vec_blocks, 256, 0, stream>>>(zbuf, sc2, sh2, h, (l < NLAYERS - 1) ? 1 : 0);
  }

  k_poolseg<<<NG, 256, 0, stream>>>(h, goff, pooled);
  k_final<<<NG, 128, 0, stream>>>(pooled, oW, ob, out);
}

// Round 7
// 1094.295 us; speedup vs baseline: 1.1448x; 1.1448x over previous
//
#include <hip/hip_runtime.h>
#include <hip/hip_fp16.h>

#define N_NODES 50000
#define N_EDGES 800000
#define HD 128
#define NLAYERS 5
#define EINC 16
#define NG 512

typedef _Float16 half8 __attribute__((ext_vector_type(8)));
typedef float f32x4 __attribute__((ext_vector_type(4)));
typedef float f32x2 __attribute__((ext_vector_type(2)));

// ---------------- embedding ----------------
__global__ __launch_bounds__(256) void k_embed(const int* __restrict__ x,
                                               const float* __restrict__ emb,
                                               float* __restrict__ h) {
  int i = blockIdx.x * 256 + threadIdx.x;
  if (i < N_NODES * 32) {
    int n = i >> 5, cv = i & 31;
    *(float4*)&h[n * HD + cv * 4] = *(const float4*)&emb[x[n] * HD + cv * 4];
  }
}

// ---------------- CSR build ----------------
__global__ __launch_bounds__(256) void k_hist(const int* __restrict__ ei,
                                              int* __restrict__ deg) {
  int e = blockIdx.x * 256 + threadIdx.x;
  if (e < N_EDGES) atomicAdd(&deg[ei[N_EDGES + e]], 1);
}

__global__ __launch_bounds__(256) void k_scan1(const int* __restrict__ deg,
                                               int* __restrict__ incl,
                                               int* __restrict__ bsum) {
  __shared__ int s[256];
  int i = blockIdx.x * 256 + threadIdx.x;
  int v = (i < N_NODES) ? deg[i] : 0;
  s[threadIdx.x] = v;
  __syncthreads();
  for (int d = 1; d < 256; d <<= 1) {
    int t = (threadIdx.x >= d) ? s[threadIdx.x - d] : 0;
    __syncthreads();
    s[threadIdx.x] += t;
    __syncthreads();
  }
  if (i < N_NODES) incl[i] = s[threadIdx.x];
  if (threadIdx.x == 255) bsum[blockIdx.x] = s[255];
}

__global__ void k_scan2(int* __restrict__ bsum, int nb) {
  __shared__ int s[256];
  int v = (threadIdx.x < nb) ? bsum[threadIdx.x] : 0;
  s[threadIdx.x] = v;
  __syncthreads();
  for (int d = 1; d < 256; d <<= 1) {
    int t = (threadIdx.x >= d) ? s[threadIdx.x - d] : 0;
    __syncthreads();
    s[threadIdx.x] += t;
    __syncthreads();
  }
  if (threadIdx.x < nb) bsum[threadIdx.x] = s[threadIdx.x];
}

__global__ __launch_bounds__(256) void k_scan3(const int* __restrict__ deg,
                                               const int* __restrict__ incl,
                                               const int* __restrict__ bsum,
                                               int* __restrict__ offs,
                                               int* __restrict__ cursor) {
  int i = blockIdx.x * 256 + threadIdx.x;
  if (i < N_NODES) {
    int base = (blockIdx.x > 0) ? bsum[blockIdx.x - 1] : 0;
    int start = base + incl[i] - deg[i];
    offs[i] = start;
    cursor[i] = start;
    if (i == N_NODES - 1) offs[N_NODES] = N_EDGES;
  }
}

__global__ __launch_bounds__(256) void k_scatter(const int* __restrict__ ei,
                                                 const float* __restrict__ ea,
                                                 int* __restrict__ cursor,
                                                 int* __restrict__ srcs,
                                                 int* __restrict__ eids,
                                                 float* __restrict__ ea_s,
                                                 int permuted) {
  int e = blockIdx.x * 256 + threadIdx.x;
  if (e < N_EDGES) {
    int dst = ei[N_EDGES + e];
    int pos = atomicAdd(&cursor[dst], 1);
    srcs[pos] = ei[e];
    eids[pos] = e;
    if (permuted) {
      float4 a0 = *(const float4*)&ea[(size_t)e * EINC];
      float4 a1 = *(const float4*)&ea[(size_t)e * EINC + 4];
      float4 a2 = *(const float4*)&ea[(size_t)e * EINC + 8];
      float4 a3 = *(const float4*)&ea[(size_t)e * EINC + 12];
      *(float4*)&ea_s[(size_t)pos * EINC] = a0;
      *(float4*)&ea_s[(size_t)pos * EINC + 4] = a1;
      *(float4*)&ea_s[(size_t)pos * EINC + 8] = a2;
      *(float4*)&ea_s[(size_t)pos * EINC + 12] = a3;
    }
  }
}

// ---------------- weight convert+transpose to fp16 (once per launch) ----------------
__global__ __launch_bounds__(256) void k_cvtw1(const float* __restrict__ W1,
                                               _Float16* __restrict__ w1t) {
  int i = blockIdx.x * 256 + threadIdx.x;
  if (i < NLAYERS * 256 * 128) {
    int l = i >> 15, r = i & 32767;
    int n = r >> 7, k = r & 127;
    w1t[i] = (_Float16)W1[(size_t)l * 32768 + k * 256 + n];
  }
}
__global__ __launch_bounds__(256) void k_cvtw2(const float* __restrict__ W2,
                                               _Float16* __restrict__ w2t) {
  int i = blockIdx.x * 256 + threadIdx.x;
  if (i < NLAYERS * 128 * 256) {
    int l = i >> 15, r = i & 32767;
    int n = r >> 8, k = r & 255;
    w2t[i] = (_Float16)W2[(size_t)l * 32768 + k * 128 + n];
  }
}

// -------- fused per-node aggregation: z = (1+eps)h + sum_in relu(h[src]+e) --------
// one wave per node; lane covers channel pair (2*lane, 2*lane+1).
// R4 structure (per-lane srcs broadcast, manual unroll) + channel-packed pk_fma.
__global__ __launch_bounds__(256) void k_aggr(const int* __restrict__ offs,
                                              const int* __restrict__ srcs,
                                              const int* __restrict__ eids,
                                              const float* __restrict__ ea,
                                              const float* __restrict__ ea_s,
                                              const float* __restrict__ W,   // [16][128]
                                              const float* __restrict__ eb,  // [128]
                                              const float* __restrict__ epsA, int layer,
                                              const float* __restrict__ h,
                                              float* __restrict__ z,
                                              int permuted) {
  const int wid = threadIdx.x >> 6;
  const int lane = threadIdx.x & 63;
  int n = blockIdx.x * 4 + wid;
  if (n >= N_NODES) return;
  const int c0 = lane * 2;

  // channel-pair weights: wp[k] = {W[k][c0], W[k][c0+1]}
  f32x2 wp[EINC];
#pragma unroll
  for (int k = 0; k < EINC; ++k) wp[k] = *(const f32x2*)&W[k * HD + c0];
  const f32x2 ebp = *(const f32x2*)&eb[c0];
  const float epsv = 1.0f + epsA[layer];
  const f32x2 zero = {0.f, 0.f};

  int j0 = offs[n], j1 = offs[n + 1];
  f32x2 hn = *(const f32x2*)&h[(size_t)n * HD + c0];
  f32x2 acc;
  acc[0] = epsv * hn[0];
  acc[1] = epsv * hn[1];

  if (permuted) {
    int j = j0;
    for (; j + 3 < j1; j += 4) {
      int js = __builtin_amdgcn_readfirstlane(j);
      const float* ra = &ea_s[(size_t)js * EINC];   // 4 contiguous rows (scalar loads)
      int s0 = srcs[j], s1 = srcs[j + 1], s2 = srcs[j + 2], s3 = srcs[j + 3];
      f32x2 g0 = *(const f32x2*)&h[(size_t)s0 * HD + c0];
      f32x2 g1 = *(const f32x2*)&h[(size_t)s1 * HD + c0];
      f32x2 g2 = *(const f32x2*)&h[(size_t)s2 * HD + c0];
      f32x2 g3 = *(const f32x2*)&h[(size_t)s3 * HD + c0];
      f32x2 e0 = ebp, e1 = ebp, e2 = ebp, e3 = ebp;
#pragma unroll
      for (int k = 0; k < EINC; ++k) {
        f32x2 w2 = wp[k];
        float a0 = ra[k], a1 = ra[EINC + k], a2 = ra[2 * EINC + k], a3 = ra[3 * EINC + k];
        f32x2 v0 = {a0, a0}, v1 = {a1, a1}, v2 = {a2, a2}, v3 = {a3, a3};
        e0 = __builtin_elementwise_fma(v0, w2, e0);
        e1 = __builtin_elementwise_fma(v1, w2, e1);
        e2 = __builtin_elementwise_fma(v2, w2, e2);
        e3 = __builtin_elementwise_fma(v3, w2, e3);
      }
      acc += __builtin_elementwise_max(g0 + e0, zero);
      acc += __builtin_elementwise_max(g1 + e1, zero);
      acc += __builtin_elementwise_max(g2 + e2, zero);
      acc += __builtin_elementwise_max(g3 + e3, zero);
    }
    for (; j < j1; ++j) {
      int js = __builtin_amdgcn_readfirstlane(j);
      const float* ra = &ea_s[(size_t)js * EINC];
      int s0 = srcs[j];
      f32x2 g0 = *(const f32x2*)&h[(size_t)s0 * HD + c0];
      f32x2 e0 = ebp;
#pragma unroll
      for (int k = 0; k < EINC; ++k) {
        float a0 = ra[k];
        f32x2 v0 = {a0, a0};
        e0 = __builtin_elementwise_fma(v0, wp[k], e0);
      }
      acc += __builtin_elementwise_max(g0 + e0, zero);
    }
  } else {
    for (int j = j0; j < j1; ++j) {
      int eid = __builtin_amdgcn_readfirstlane(eids[j]);
      const float* ra = &ea[(size_t)eid * EINC];
      int s0 = srcs[j];
      f32x2 g0 = *(const f32x2*)&h[(size_t)s0 * HD + c0];
      f32x2 e0 = ebp;
#pragma unroll
      for (int k = 0; k < EINC; ++k) {
        float a0 = ra[k];
        f32x2 v0 = {a0, a0};
        e0 = __builtin_elementwise_fma(v0, wp[k], e0);
      }
      acc += __builtin_elementwise_max(g0 + e0, zero);
    }
  }
  *(f32x2*)&z[(size_t)n * HD + c0] = acc;
}

// ---------- GEMM1 (MFMA fp16): y1h = fp16(z @ W1 + b1) ; col stats ----------
__global__ __launch_bounds__(256) void k_gemm1m(const float* __restrict__ z,
                                                const _Float16* __restrict__ w1t, // [256][128]
                                                const float* __restrict__ bias,   // [256]
                                                _Float16* __restrict__ y1h,
                                                float* __restrict__ gsum,
                                                float* __restrict__ gsq) {
  __shared__ _Float16 sA[128 * 40];
  __shared__ _Float16 sBT[128 * 40];
  __shared__ float ssum[128], ssq[128];
  const int tid = threadIdx.x;
  const int lane = tid & 63;
  const int wid = tid >> 6;
  const int wm = wid >> 1, wn = wid & 1;
  const int m0 = blockIdx.x * 128;
  const int n0 = blockIdx.y * 128;

  if (tid < 128) { ssum[tid] = 0.f; ssq[tid] = 0.f; }

  f32x4 acc[4][4];
  const f32x4 zz = {0.f, 0.f, 0.f, 0.f};
#pragma unroll
  for (int a = 0; a < 4; ++a)
#pragma unroll
    for (int b = 0; b < 4; ++b) acc[a][b] = zz;

  const int srow = tid >> 1;
  const int skh = (tid & 1) * 16;

  for (int k0 = 0; k0 < 128; k0 += 32) {
    {
      int n = m0 + srow;
      half8 p0, p1;
      if (n < N_NODES) {
        float4 a0 = *(const float4*)&z[(size_t)n * 128 + k0 + skh + 0];
        float4 a1 = *(const float4*)&z[(size_t)n * 128 + k0 + skh + 4];
        float4 a2 = *(const float4*)&z[(size_t)n * 128 + k0 + skh + 8];
        float4 a3 = *(const float4*)&z[(size_t)n * 128 + k0 + skh + 12];
        p0[0] = (_Float16)a0.x; p0[1] = (_Float16)a0.y; p0[2] = (_Float16)a0.z; p0[3] = (_Float16)a0.w;
        p0[4] = (_Float16)a1.x; p0[5] = (_Float16)a1.y; p0[6] = (_Float16)a1.z; p0[7] = (_Float16)a1.w;
        p1[0] = (_Float16)a2.x; p1[1] = (_Float16)a2.y; p1[2] = (_Float16)a2.z; p1[3] = (_Float16)a2.w;
        p1[4] = (_Float16)a3.x; p1[5] = (_Float16)a3.y; p1[6] = (_Float16)a3.z; p1[7] = (_Float16)a3.w;
      } else {
#pragma unroll
        for (int j = 0; j < 8; ++j) { p0[j] = (_Float16)0.f; p1[j] = (_Float16)0.f; }
      }
      *(half8*)&sA[srow * 40 + skh] = p0;
      *(half8*)&sA[srow * 40 + skh + 8] = p1;
    }
    {
      half8 u0 = *(const half8*)&w1t[(size_t)(n0 + srow) * 128 + k0 + skh];
      half8 u1 = *(const half8*)&w1t[(size_t)(n0 + srow) * 128 + k0 + skh + 8];
      *(half8*)&sBT[srow * 40 + skh] = u0;
      *(half8*)&sBT[srow * 40 + skh + 8] = u1;
    }
    __syncthreads();
    half8 af[4], bf[4];
#pragma unroll
    for (int t = 0; t < 4; ++t) {
      af[t] = *(const half8*)&sA[(wm * 64 + t * 16 + (lane & 15)) * 40 + (lane >> 4) * 8];
      bf[t] = *(const half8*)&sBT[(wn * 64 + t * 16 + (lane & 15)) * 40 + (lane >> 4) * 8];
    }
#pragma unroll
    for (int tm = 0; tm < 4; ++tm)
#pragma unroll
      for (int tn = 0; tn < 4; ++tn)
        acc[tm][tn] = __builtin_amdgcn_mfma_f32_16x16x32_f16(af[tm], bf[tn], acc[tm][tn], 0, 0, 0);
    __syncthreads();
  }

  float bsv[4];
#pragma unroll
  for (int tn = 0; tn < 4; ++tn) bsv[tn] = bias[n0 + wn * 64 + tn * 16 + (lane & 15)];
  float sacc[4] = {0.f, 0.f, 0.f, 0.f}, qacc[4] = {0.f, 0.f, 0.f, 0.f};
#pragma unroll
  for (int tm = 0; tm < 4; ++tm) {
    int nbase = m0 + wm * 64 + tm * 16 + (lane >> 4) * 4;
#pragma unroll
    for (int r = 0; r < 4; ++r) {
      int n = nbase + r;
      if (n < N_NODES) {
#pragma unroll
        for (int tn = 0; tn < 4; ++tn) {
          float v = acc[tm][tn][r] + bsv[tn];
          y1h[(size_t)n * 256 + n0 + wn * 64 + tn * 16 + (lane & 15)] = (_Float16)v;
          sacc[tn] += v; qacc[tn] += v * v;
        }
      }
    }
  }
#pragma unroll
  for (int tn = 0; tn < 4; ++tn) {
    int c = wn * 64 + tn * 16 + (lane & 15);
    atomicAdd(&ssum[c], sacc[tn]);
    atomicAdd(&ssq[c], qacc[tn]);
  }
  __syncthreads();
  if (tid < 128) {
    unsafeAtomicAdd(&gsum[n0 + tid], ssum[tid]);
    unsafeAtomicAdd(&gsq[n0 + tid], ssq[tid]);
  }
}

// ---------- GEMM2 (MFMA fp16): y2 = relu(bn1(y1h)) @ W2 + b2 ; col stats ----------
__global__ __launch_bounds__(256) void k_gemm2m(const _Float16* __restrict__ y1h,
                                                const float* __restrict__ sc,
                                                const float* __restrict__ sh,
                                                const _Float16* __restrict__ w2t, // [128][256]
                                                const float* __restrict__ bias,   // [128]
                                                float* __restrict__ y2,
                                                float* __restrict__ gsum,
                                                float* __restrict__ gsq) {
  __shared__ _Float16 sA[64 * 40];
  __shared__ _Float16 sBT[128 * 40];
  __shared__ float ssc[256], ssh[256];
  __shared__ float ssum[128], ssq[128];
  const int tid = threadIdx.x;
  const int lane = tid & 63;
  const int wid = tid >> 6;
  const int wm = wid >> 1, wn = wid & 1;
  const int m0 = blockIdx.x * 64;

  ssc[tid] = sc[tid];
  ssh[tid] = sh[tid];
  if (tid < 128) { ssum[tid] = 0.f; ssq[tid] = 0.f; }
  __syncthreads();

  f32x4 acc[2][4];
  const f32x4 zz = {0.f, 0.f, 0.f, 0.f};
#pragma unroll
  for (int a = 0; a < 2; ++a)
#pragma unroll
    for (int b = 0; b < 4; ++b) acc[a][b] = zz;

  const int arow = tid >> 2;
  const int akq = (tid & 3) * 8;
  const int brow = tid >> 1;
  const int bkh = (tid & 1) * 16;

  for (int k0 = 0; k0 < 256; k0 += 32) {
    {
      int n = m0 + arow;
      half8 p;
      if (n < N_NODES) {
        half8 yv = *(const half8*)&y1h[(size_t)n * 256 + k0 + akq];
#pragma unroll
        for (int j = 0; j < 8; ++j) {
          float v = fmaxf((float)yv[j] * ssc[k0 + akq + j] + ssh[k0 + akq + j], 0.f);
          p[j] = (_Float16)v;
        }
      } else {
#pragma unroll
        for (int j = 0; j < 8; ++j) p[j] = (_Float16)0.f;
      }
      *(half8*)&sA[arow * 40 + akq] = p;
    }
    {
      half8 u0 = *(const half8*)&w2t[(size_t)brow * 256 + k0 + bkh];
      half8 u1 = *(const half8*)&w2t[(size_t)brow * 256 + k0 + bkh + 8];
      *(half8*)&sBT[brow * 40 + bkh] = u0;
      *(half8*)&sBT[brow * 40 + bkh + 8] = u1;
    }
    __syncthreads();
    half8 af[2], bf[4];
#pragma unroll
    for (int t = 0; t < 2; ++t)
      af[t] = *(const half8*)&sA[(wm * 32 + t * 16 + (lane & 15)) * 40 + (lane >> 4) * 8];
#pragma unroll
    for (int t = 0; t < 4; ++t)
      bf[t] = *(const half8*)&sBT[(wn * 64 + t * 16 + (lane & 15)) * 40 + (lane >> 4) * 8];
#pragma unroll
    for (int tm = 0; tm < 2; ++tm)
#pragma unroll
      for (int tn = 0; tn < 4; ++tn)
        acc[tm][tn] = __builtin_amdgcn_mfma_f32_16x16x32_f16(af[tm], bf[tn], acc[tm][tn], 0, 0, 0);
    __syncthreads();
  }

  float bsv[4];
#pragma unroll
  for (int tn = 0; tn < 4; ++tn) bsv[tn] = bias[wn * 64 + tn * 16 + (lane & 15)];
  float sacc[4] = {0.f, 0.f, 0.f, 0.f}, qacc[4] = {0.f, 0.f, 0.f, 0.f};
#pragma unroll
  for (int tm = 0; tm < 2; ++tm) {
    int nbase = m0 + wm * 32 + tm * 16 + (lane >> 4) * 4;
#pragma unroll
    for (int r = 0; r < 4; ++r) {
      int n = nbase + r;
      if (n < N_NODES) {
#pragma unroll
        for (int tn = 0; tn < 4; ++tn) {
          float v = acc[tm][tn][r] + bsv[tn];
          y2[(size_t)n * 128 + wn * 64 + tn * 16 + (lane & 15)] = v;
          sacc[tn] += v; qacc[tn] += v * v;
        }
      }
    }
  }
#pragma unroll
  for (int tn = 0; tn < 4; ++tn) {
    int c = wn * 64 + tn * 16 + (lane & 15);
    atomicAdd(&ssum[c], sacc[tn]);
    atomicAdd(&ssq[c], qacc[tn]);
  }
  __syncthreads();
  if (tid < 128) {
    unsafeAtomicAdd(&gsum[tid], ssum[tid]);
    unsafeAtomicAdd(&gsq[tid], ssq[tid]);
  }
}

// ---------------- BN finalize ----------------
__global__ void k_bnfin(const float* __restrict__ sum, const float* __restrict__ sq,
                        const float* __restrict__ g, const float* __restrict__ b,
                        float* __restrict__ sc, float* __restrict__ sh, int C) {
  int c = blockIdx.x * blockDim.x + threadIdx.x;
  if (c < C) {
    const float invN = 1.0f / (float)N_NODES;
    float m = sum[c] * invN;
    float v = fmaxf(sq[c] * invN - m * m, 0.0f);
    float rs = rsqrtf(v + 1e-5f);
    float scale = g[c] * rs;
    sc[c] = scale;
    sh[c] = b[c] - m * scale;
  }
}

// ---------------- apply BN (+optional relu) ----------------
__global__ __launch_bounds__(256) void k_bnapply(const float* __restrict__ y2,
                                                 const float* __restrict__ sc,
                                                 const float* __restrict__ sh,
                                                 float* __restrict__ h, int dorelu) {
  int i = blockIdx.x * 256 + threadIdx.x;
  if (i < N_NODES * 32) {
    int cv = i & 31;
    float4 v = *(const float4*)&y2[i * 4];
    float4 s4 = *(const float4*)&sc[cv * 4];
    float4 h4 = *(const float4*)&sh[cv * 4];
    float4 o;
    o.x = v.x * s4.x + h4.x; o.y = v.y * s4.y + h4.y;
    o.z = v.z * s4.z + h4.z; o.w = v.w * s4.w + h4.w;
    if (dorelu) {
      o.x = fmaxf(o.x, 0.f); o.y = fmaxf(o.y, 0.f);
      o.z = fmaxf(o.z, 0.f); o.w = fmaxf(o.w, 0.f);
    }
    *(float4*)&h[i * 4] = o;
  }
}

// ---------------- pooling: sorted-batch segment reduction ----------------
__global__ void k_goff(const int* __restrict__ batch, int* __restrict__ goff) {
  int g = blockIdx.x * blockDim.x + threadIdx.x;
  if (g <= NG) {
    if (g == NG) { goff[g] = N_NODES; return; }
    int lo = 0, hi = N_NODES;
    while (lo < hi) { int mid = (lo + hi) >> 1; if (batch[mid] < g) lo = mid + 1; else hi = mid; }
    goff[g] = lo;
  }
}

__global__ __launch_bounds__(256) void k_poolseg(const float* __restrict__ h,
                                                 const int* __restrict__ goff,
                                                 float* __restrict__ pooled) {
  __shared__ float sred[256];
  int g = blockIdx.x;
  int c = threadIdx.x & 127;
  int half = threadIdx.x >> 7;
  int n0 = goff[g], n1 = goff[g + 1];
  float s = 0.f;
  for (int n = n0 + half; n < n1; n += 2) s += h[(size_t)n * HD + c];
  sred[threadIdx.x] = s;
  __syncthreads();
  if (threadIdx.x < 128) {
    float tot = sred[threadIdx.x] + sred[threadIdx.x + 128];
    float cntf = (float)(n1 - n0);
    pooled[g * HD + threadIdx.x] = tot / fmaxf(cntf, 1.0f);
  }
}

// ---------------- final GEMM ----------------
__global__ __launch_bounds__(128) void k_final(const float* __restrict__ pooled,
                                               const float* __restrict__ oW,
                                               const float* __restrict__ ob,
                                               float* __restrict__ out) {
  __shared__ float sP[HD];
  int g = blockIdx.x;
  int c = threadIdx.x;
  sP[c] = pooled[g * HD + c];
  __syncthreads();
  float acc = ob[c];
#pragma unroll 8
  for (int k = 0; k < HD; ++k) acc += sP[k] * oW[k * HD + c];
  out[g * HD + c] = acc;
}

extern "C" void kernel_launch(void* const* d_in, const int* in_sizes, int n_in,
                              void* d_out, int out_size, void* d_ws, size_t ws_size,
                              hipStream_t stream) {
  const int* x = (const int*)d_in[0];
  const int* ei = (const int*)d_in[1];
  const float* ea = (const float*)d_in[2];
  const int* batch = (const int*)d_in[3];
  const float* emb = (const float*)d_in[4];
  const float* eW = (const float*)d_in[5];
  const float* eb = (const float*)d_in[6];
  const float* epsA = (const float*)d_in[7];
  const float* W1 = (const float*)d_in[8];
  const float* b1 = (const float*)d_in[9];
  const float* g1 = (const float*)d_in[10];
  const float* be1 = (const float*)d_in[11];
  const float* W2 = (const float*)d_in[12];
  const float* b2 = (const float*)d_in[13];
  const float* bng = (const float*)d_in[14];
  const float* bnb = (const float*)d_in[15];
  const float* oW = (const float*)d_in[16];
  const float* ob = (const float*)d_in[17];
  float* out = (float*)d_out;

  // ----- workspace layout: ints first, then floats -----
  int* ip = (int*)d_ws;
  int* deg = ip;                         // 50,000
  int* incl = deg + 50000;               // 50,000
  int* offs = incl + 50000;              // 50,001
  int* cursor = offs + 50001;            // 50,000
  int* srcs = cursor + 50000;            // 800,000
  int* eids = srcs + 800000;             // 800,000
  int* bsum = eids + 800000;             // 200
  int* goff = bsum + 200;                // 513
  float* fp = (float*)(ip + 1800916);
  float* h = fp;                         // 6,400,000
  float* zbuf = h + 6400000;             // 6,400,000 (z and y2 alias)
  _Float16* y1h = (_Float16*)(zbuf + 6400000);  // 12,800,000 halves
  float* stats = zbuf + 12800000;        // 768
  float* sc1 = stats + 768;              // 256
  float* sh1 = sc1 + 256;                // 256
  float* sc2 = sh1 + 256;                // 128
  float* sh2 = sc2 + 128;                // 128
  float* pooled = sh2 + 128;             // 65,536
  _Float16* w1t = (_Float16*)(pooled + 65536);  // 163,840 halves
  _Float16* w2t = w1t + 163840;                 // 163,840 halves
  float* ea_s = pooled + 65536 + 163840;        // 12,800,000 (optional)

  size_t needed_with = (size_t)(ea_s + 12800000 - (float*)d_ws) * 4;
  int permuted = (ws_size >= needed_with) ? 1 : 0;

  const int vec_blocks = (N_NODES * 32 + 255) / 256;
  const int edge_blocks = (N_EDGES + 255) / 256;
  const int node_blocks = (N_NODES + 255) / 256;

  k_embed<<<vec_blocks, 256, 0, stream>>>(x, emb, h);

  // CSR build + weight conversion (once per launch)
  hipMemsetAsync(deg, 0, 50000 * sizeof(int), stream);
  k_hist<<<edge_blocks, 256, 0, stream>>>(ei, deg);
  k_scan1<<<node_blocks, 256, 0, stream>>>(deg, incl, bsum);
  k_scan2<<<1, 256, 0, stream>>>(bsum, node_blocks);
  k_scan3<<<node_blocks, 256, 0, stream>>>(deg, incl, bsum, offs, cursor);
  k_scatter<<<edge_blocks, 256, 0, stream>>>(ei, ea, cursor, srcs, eids, ea_s, permuted);
  k_goff<<<3, 256, 0, stream>>>(batch, goff);
  k_cvtw1<<<640, 256, 0, stream>>>(W1, w1t);
  k_cvtw2<<<640, 256, 0, stream>>>(W2, w2t);

  for (int l = 0; l < NLAYERS; ++l) {
    hipMemsetAsync(stats, 0, 768 * sizeof(float), stream);
    k_aggr<<<(N_NODES + 3) / 4, 256, 0, stream>>>(offs, srcs, eids, ea, ea_s,
                                                  eW + (size_t)l * EINC * HD, eb + l * HD,
                                                  epsA, l, h, zbuf, permuted);
    k_gemm1m<<<dim3(391, 2), 256, 0, stream>>>(zbuf, w1t + (size_t)l * 32768,
                                               b1 + l * 256, y1h, stats, stats + 256);
    k_bnfin<<<1, 256, 0, stream>>>(stats, stats + 256, g1 + l * 256, be1 + l * 256, sc1, sh1, 256);
    k_gemm2m<<<782, 256, 0, stream>>>(y1h, sc1, sh1, w2t + (size_t)l * 32768,
                                      b2 + l * HD, zbuf, stats + 512, stats + 640);
    k_bnfin<<<1, 128, 0, stream>>>(stats + 512, stats + 640, bng + l * HD, bnb + l * HD, sc2, sh2, 128);
    k_bnapply<<<vec_blocks, 256, 0, stream>>>(zbuf, sc2, sh2, h, (l < NLAYERS - 1) ? 1 : 0);
  }

  k_poolseg<<<NG, 256, 0, stream>>>(h, goff, pooled);
  k_final<<<NG, 128, 0, stream>>>(pooled, oW, ob, out);
}

// Round 8
// 1070.838 us; speedup vs baseline: 1.1698x; 1.0219x over previous
//
#include <hip/hip_runtime.h>
#include <hip/hip_fp16.h>

#define N_NODES 50000
#define N_EDGES 800000
#define HD 128
#define NLAYERS 5
#define EINC 16
#define NG 512

typedef _Float16 half8 __attribute__((ext_vector_type(8)));
typedef float f32x4 __attribute__((ext_vector_type(4)));
typedef float f32x2 __attribute__((ext_vector_type(2)));

// ---------------- embedding ----------------
__global__ __launch_bounds__(256) void k_embed(const int* __restrict__ x,
                                               const float* __restrict__ emb,
                                               float* __restrict__ h) {
  int i = blockIdx.x * 256 + threadIdx.x;
  if (i < N_NODES * 32) {
    int n = i >> 5, cv = i & 31;
    *(float4*)&h[n * HD + cv * 4] = *(const float4*)&emb[x[n] * HD + cv * 4];
  }
}

// ---------------- CSR build ----------------
__global__ __launch_bounds__(256) void k_hist(const int* __restrict__ ei,
                                              int* __restrict__ deg) {
  int e = blockIdx.x * 256 + threadIdx.x;
  if (e < N_EDGES) atomicAdd(&deg[ei[N_EDGES + e]], 1);
}

__global__ __launch_bounds__(256) void k_scan1(const int* __restrict__ deg,
                                               int* __restrict__ incl,
                                               int* __restrict__ bsum) {
  __shared__ int s[256];
  int i = blockIdx.x * 256 + threadIdx.x;
  int v = (i < N_NODES) ? deg[i] : 0;
  s[threadIdx.x] = v;
  __syncthreads();
  for (int d = 1; d < 256; d <<= 1) {
    int t = (threadIdx.x >= d) ? s[threadIdx.x - d] : 0;
    __syncthreads();
    s[threadIdx.x] += t;
    __syncthreads();
  }
  if (i < N_NODES) incl[i] = s[threadIdx.x];
  if (threadIdx.x == 255) bsum[blockIdx.x] = s[255];
}

__global__ void k_scan2(int* __restrict__ bsum, int nb) {
  __shared__ int s[256];
  int v = (threadIdx.x < nb) ? bsum[threadIdx.x] : 0;
  s[threadIdx.x] = v;
  __syncthreads();
  for (int d = 1; d < 256; d <<= 1) {
    int t = (threadIdx.x >= d) ? s[threadIdx.x - d] : 0;
    __syncthreads();
    s[threadIdx.x] += t;
    __syncthreads();
  }
  if (threadIdx.x < nb) bsum[threadIdx.x] = s[threadIdx.x];
}

__global__ __launch_bounds__(256) void k_scan3(const int* __restrict__ deg,
                                               const int* __restrict__ incl,
                                               const int* __restrict__ bsum,
                                               int* __restrict__ offs,
                                               int* __restrict__ cursor) {
  int i = blockIdx.x * 256 + threadIdx.x;
  if (i < N_NODES) {
    int base = (blockIdx.x > 0) ? bsum[blockIdx.x - 1] : 0;
    int start = base + incl[i] - deg[i];
    offs[i] = start;
    cursor[i] = start;
    if (i == N_NODES - 1) offs[N_NODES] = N_EDGES;
  }
}

__global__ __launch_bounds__(256) void k_scatter(const int* __restrict__ ei,
                                                 const float* __restrict__ ea,
                                                 int* __restrict__ cursor,
                                                 int* __restrict__ srcs,
                                                 int* __restrict__ eids,
                                                 float* __restrict__ ea_s,
                                                 int permuted) {
  int e = blockIdx.x * 256 + threadIdx.x;
  if (e < N_EDGES) {
    int dst = ei[N_EDGES + e];
    int pos = atomicAdd(&cursor[dst], 1);
    srcs[pos] = ei[e];
    if (permuted) {
      float4 a0 = *(const float4*)&ea[(size_t)e * EINC];
      float4 a1 = *(const float4*)&ea[(size_t)e * EINC + 4];
      float4 a2 = *(const float4*)&ea[(size_t)e * EINC + 8];
      float4 a3 = *(const float4*)&ea[(size_t)e * EINC + 12];
      *(float4*)&ea_s[(size_t)pos * EINC] = a0;
      *(float4*)&ea_s[(size_t)pos * EINC + 4] = a1;
      *(float4*)&ea_s[(size_t)pos * EINC + 8] = a2;
      *(float4*)&ea_s[(size_t)pos * EINC + 12] = a3;
    } else {
      eids[pos] = e;
    }
  }
}

// ---------------- weight convert+transpose to fp16 (once per launch) ----------------
__global__ __launch_bounds__(256) void k_cvtw1(const float* __restrict__ W1,
                                               _Float16* __restrict__ w1t) {
  int i = blockIdx.x * 256 + threadIdx.x;
  if (i < NLAYERS * 256 * 128) {
    int l = i >> 15, r = i & 32767;
    int n = r >> 7, k = r & 127;
    w1t[i] = (_Float16)W1[(size_t)l * 32768 + k * 256 + n];
  }
}
__global__ __launch_bounds__(256) void k_cvtw2(const float* __restrict__ W2,
                                               _Float16* __restrict__ w2t) {
  int i = blockIdx.x * 256 + threadIdx.x;
  if (i < NLAYERS * 128 * 256) {
    int l = i >> 15, r = i & 32767;
    int n = r >> 8, k = r & 255;
    w2t[i] = (_Float16)W2[(size_t)l * 32768 + k * 128 + n];
  }
}

// -------- fused per-node aggregation with fused inter-layer BN+ReLU --------
// h_eff = fuse_bn ? relu(hraw*sc+sh) : hraw ;  z = (1+eps)h_eff(n) + sum_in relu(h_eff(src)+e)
// one wave per node; lane covers channel pair (2*lane, 2*lane+1).
__global__ __launch_bounds__(256) void k_aggr(const int* __restrict__ offs,
                                              const int* __restrict__ srcs,
                                              const int* __restrict__ eids,
                                              const float* __restrict__ ea,
                                              const float* __restrict__ ea_s,
                                              const float* __restrict__ W,   // [16][128]
                                              const float* __restrict__ eb,  // [128]
                                              const float* __restrict__ epsA, int layer,
                                              const float* __restrict__ hraw,
                                              const float* __restrict__ bnsc,
                                              const float* __restrict__ bnsh,
                                              int fuse_bn,
                                              float* __restrict__ z,
                                              int permuted) {
  const int wid = threadIdx.x >> 6;
  const int lane = threadIdx.x & 63;
  int n = blockIdx.x * 4 + wid;
  if (n >= N_NODES) return;
  const int c0 = lane * 2;

  // channel-pair weights: wp[k] = {W[k][c0], W[k][c0+1]}
  f32x2 wp[EINC];
#pragma unroll
  for (int k = 0; k < EINC; ++k) wp[k] = *(const f32x2*)&W[k * HD + c0];
  const f32x2 ebp = *(const f32x2*)&eb[c0];
  const float epsv = 1.0f + epsA[layer];
  const f32x2 zero = {0.f, 0.f};
  f32x2 scp = {1.f, 1.f}, shp = {0.f, 0.f};
  if (fuse_bn) {
    scp = *(const f32x2*)&bnsc[c0];
    shp = *(const f32x2*)&bnsh[c0];
  }

  int j0 = offs[n], j1 = offs[n + 1];
  f32x2 hn = *(const f32x2*)&hraw[(size_t)n * HD + c0];
  if (fuse_bn) hn = __builtin_elementwise_max(__builtin_elementwise_fma(hn, scp, shp), zero);
  f32x2 acc;
  acc[0] = epsv * hn[0];
  acc[1] = epsv * hn[1];

  if (permuted) {
    int j = j0;
    for (; j + 3 < j1; j += 4) {
      int js = __builtin_amdgcn_readfirstlane(j);
      const float* ra = &ea_s[(size_t)js * EINC];   // 4 contiguous rows (scalar loads)
      int s0 = srcs[j], s1 = srcs[j + 1], s2 = srcs[j + 2], s3 = srcs[j + 3];
      f32x2 g0 = *(const f32x2*)&hraw[(size_t)s0 * HD + c0];
      f32x2 g1 = *(const f32x2*)&hraw[(size_t)s1 * HD + c0];
      f32x2 g2 = *(const f32x2*)&hraw[(size_t)s2 * HD + c0];
      f32x2 g3 = *(const f32x2*)&hraw[(size_t)s3 * HD + c0];
      if (fuse_bn) {
        g0 = __builtin_elementwise_max(__builtin_elementwise_fma(g0, scp, shp), zero);
        g1 = __builtin_elementwise_max(__builtin_elementwise_fma(g1, scp, shp), zero);
        g2 = __builtin_elementwise_max(__builtin_elementwise_fma(g2, scp, shp), zero);
        g3 = __builtin_elementwise_max(__builtin_elementwise_fma(g3, scp, shp), zero);
      }
      f32x2 e0 = ebp, e1 = ebp, e2 = ebp, e3 = ebp;
#pragma unroll
      for (int k = 0; k < EINC; ++k) {
        f32x2 w2 = wp[k];
        float a0 = ra[k], a1 = ra[EINC + k], a2 = ra[2 * EINC + k], a3 = ra[3 * EINC + k];
        f32x2 v0 = {a0, a0}, v1 = {a1, a1}, v2 = {a2, a2}, v3 = {a3, a3};
        e0 = __builtin_elementwise_fma(v0, w2, e0);
        e1 = __builtin_elementwise_fma(v1, w2, e1);
        e2 = __builtin_elementwise_fma(v2, w2, e2);
        e3 = __builtin_elementwise_fma(v3, w2, e3);
      }
      acc += __builtin_elementwise_max(g0 + e0, zero);
      acc += __builtin_elementwise_max(g1 + e1, zero);
      acc += __builtin_elementwise_max(g2 + e2, zero);
      acc += __builtin_elementwise_max(g3 + e3, zero);
    }
    for (; j < j1; ++j) {
      int js = __builtin_amdgcn_readfirstlane(j);
      const float* ra = &ea_s[(size_t)js * EINC];
      int s0 = srcs[j];
      f32x2 g0 = *(const f32x2*)&hraw[(size_t)s0 * HD + c0];
      if (fuse_bn) g0 = __builtin_elementwise_max(__builtin_elementwise_fma(g0, scp, shp), zero);
      f32x2 e0 = ebp;
#pragma unroll
      for (int k = 0; k < EINC; ++k) {
        float a0 = ra[k];
        f32x2 v0 = {a0, a0};
        e0 = __builtin_elementwise_fma(v0, wp[k], e0);
      }
      acc += __builtin_elementwise_max(g0 + e0, zero);
    }
  } else {
    for (int j = j0; j < j1; ++j) {
      int eid = __builtin_amdgcn_readfirstlane(eids[j]);
      const float* ra = &ea[(size_t)eid * EINC];
      int s0 = srcs[j];
      f32x2 g0 = *(const f32x2*)&hraw[(size_t)s0 * HD + c0];
      if (fuse_bn) g0 = __builtin_elementwise_max(__builtin_elementwise_fma(g0, scp, shp), zero);
      f32x2 e0 = ebp;
#pragma unroll
      for (int k = 0; k < EINC; ++k) {
        float a0 = ra[k];
        f32x2 v0 = {a0, a0};
        e0 = __builtin_elementwise_fma(v0, wp[k], e0);
      }
      acc += __builtin_elementwise_max(g0 + e0, zero);
    }
  }
  *(f32x2*)&z[(size_t)n * HD + c0] = acc;
}

// ---------- GEMM1 (MFMA fp16): y1h = fp16(z @ W1 + b1) ; col stats ----------
__global__ __launch_bounds__(256) void k_gemm1m(const float* __restrict__ z,
                                                const _Float16* __restrict__ w1t, // [256][128]
                                                const float* __restrict__ bias,   // [256]
                                                _Float16* __restrict__ y1h,
                                                float* __restrict__ gsum,
                                                float* __restrict__ gsq) {
  __shared__ _Float16 sA[128 * 40];
  __shared__ _Float16 sBT[128 * 40];
  __shared__ float ssum[128], ssq[128];
  const int tid = threadIdx.x;
  const int lane = tid & 63;
  const int wid = tid >> 6;
  const int wm = wid >> 1, wn = wid & 1;
  const int m0 = blockIdx.x * 128;
  const int n0 = blockIdx.y * 128;

  if (tid < 128) { ssum[tid] = 0.f; ssq[tid] = 0.f; }

  f32x4 acc[4][4];
  const f32x4 zz = {0.f, 0.f, 0.f, 0.f};
#pragma unroll
  for (int a = 0; a < 4; ++a)
#pragma unroll
    for (int b = 0; b < 4; ++b) acc[a][b] = zz;

  const int srow = tid >> 1;
  const int skh = (tid & 1) * 16;

  for (int k0 = 0; k0 < 128; k0 += 32) {
    {
      int n = m0 + srow;
      half8 p0, p1;
      if (n < N_NODES) {
        float4 a0 = *(const float4*)&z[(size_t)n * 128 + k0 + skh + 0];
        float4 a1 = *(const float4*)&z[(size_t)n * 128 + k0 + skh + 4];
        float4 a2 = *(const float4*)&z[(size_t)n * 128 + k0 + skh + 8];
        float4 a3 = *(const float4*)&z[(size_t)n * 128 + k0 + skh + 12];
        p0[0] = (_Float16)a0.x; p0[1] = (_Float16)a0.y; p0[2] = (_Float16)a0.z; p0[3] = (_Float16)a0.w;
        p0[4] = (_Float16)a1.x; p0[5] = (_Float16)a1.y; p0[6] = (_Float16)a1.z; p0[7] = (_Float16)a1.w;
        p1[0] = (_Float16)a2.x; p1[1] = (_Float16)a2.y; p1[2] = (_Float16)a2.z; p1[3] = (_Float16)a2.w;
        p1[4] = (_Float16)a3.x; p1[5] = (_Float16)a3.y; p1[6] = (_Float16)a3.z; p1[7] = (_Float16)a3.w;
      } else {
#pragma unroll
        for (int j = 0; j < 8; ++j) { p0[j] = (_Float16)0.f; p1[j] = (_Float16)0.f; }
      }
      *(half8*)&sA[srow * 40 + skh] = p0;
      *(half8*)&sA[srow * 40 + skh + 8] = p1;
    }
    {
      half8 u0 = *(const half8*)&w1t[(size_t)(n0 + srow) * 128 + k0 + skh];
      half8 u1 = *(const half8*)&w1t[(size_t)(n0 + srow) * 128 + k0 + skh + 8];
      *(half8*)&sBT[srow * 40 + skh] = u0;
      *(half8*)&sBT[srow * 40 + skh + 8] = u1;
    }
    __syncthreads();
    half8 af[4], bf[4];
#pragma unroll
    for (int t = 0; t < 4; ++t) {
      af[t] = *(const half8*)&sA[(wm * 64 + t * 16 + (lane & 15)) * 40 + (lane >> 4) * 8];
      bf[t] = *(const half8*)&sBT[(wn * 64 + t * 16 + (lane & 15)) * 40 + (lane >> 4) * 8];
    }
#pragma unroll
    for (int tm = 0; tm < 4; ++tm)
#pragma unroll
      for (int tn = 0; tn < 4; ++tn)
        acc[tm][tn] = __builtin_amdgcn_mfma_f32_16x16x32_f16(af[tm], bf[tn], acc[tm][tn], 0, 0, 0);
    __syncthreads();
  }

  float bsv[4];
#pragma unroll
  for (int tn = 0; tn < 4; ++tn) bsv[tn] = bias[n0 + wn * 64 + tn * 16 + (lane & 15)];
  float sacc[4] = {0.f, 0.f, 0.f, 0.f}, qacc[4] = {0.f, 0.f, 0.f, 0.f};
#pragma unroll
  for (int tm = 0; tm < 4; ++tm) {
    int nbase = m0 + wm * 64 + tm * 16 + (lane >> 4) * 4;
#pragma unroll
    for (int r = 0; r < 4; ++r) {
      int n = nbase + r;
      if (n < N_NODES) {
#pragma unroll
        for (int tn = 0; tn < 4; ++tn) {
          float v = acc[tm][tn][r] + bsv[tn];
          y1h[(size_t)n * 256 + n0 + wn * 64 + tn * 16 + (lane & 15)] = (_Float16)v;
          sacc[tn] += v; qacc[tn] += v * v;
        }
      }
    }
  }
#pragma unroll
  for (int tn = 0; tn < 4; ++tn) {
    int c = wn * 64 + tn * 16 + (lane & 15);
    atomicAdd(&ssum[c], sacc[tn]);
    atomicAdd(&ssq[c], qacc[tn]);
  }
  __syncthreads();
  if (tid < 128) {
    unsafeAtomicAdd(&gsum[n0 + tid], ssum[tid]);
    unsafeAtomicAdd(&gsq[n0 + tid], ssq[tid]);
  }
}

// ---------- GEMM2 (MFMA fp16): y2 = relu(bn1(y1h)) @ W2 + b2 ; col stats ----------
__global__ __launch_bounds__(256) void k_gemm2m(const _Float16* __restrict__ y1h,
                                                const float* __restrict__ sc,
                                                const float* __restrict__ sh,
                                                const _Float16* __restrict__ w2t, // [128][256]
                                                const float* __restrict__ bias,   // [128]
                                                float* __restrict__ y2,
                                                float* __restrict__ gsum,
                                                float* __restrict__ gsq) {
  __shared__ _Float16 sA[64 * 40];
  __shared__ _Float16 sBT[128 * 40];
  __shared__ float ssc[256], ssh[256];
  __shared__ float ssum[128], ssq[128];
  const int tid = threadIdx.x;
  const int lane = tid & 63;
  const int wid = tid >> 6;
  const int wm = wid >> 1, wn = wid & 1;
  const int m0 = blockIdx.x * 64;

  ssc[tid] = sc[tid];
  ssh[tid] = sh[tid];
  if (tid < 128) { ssum[tid] = 0.f; ssq[tid] = 0.f; }
  __syncthreads();

  f32x4 acc[2][4];
  const f32x4 zz = {0.f, 0.f, 0.f, 0.f};
#pragma unroll
  for (int a = 0; a < 2; ++a)
#pragma unroll
    for (int b = 0; b < 4; ++b) acc[a][b] = zz;

  const int arow = tid >> 2;
  const int akq = (tid & 3) * 8;
  const int brow = tid >> 1;
  const int bkh = (tid & 1) * 16;

  for (int k0 = 0; k0 < 256; k0 += 32) {
    {
      int n = m0 + arow;
      half8 p;
      if (n < N_NODES) {
        half8 yv = *(const half8*)&y1h[(size_t)n * 256 + k0 + akq];
#pragma unroll
        for (int j = 0; j < 8; ++j) {
          float v = fmaxf((float)yv[j] * ssc[k0 + akq + j] + ssh[k0 + akq + j], 0.f);
          p[j] = (_Float16)v;
        }
      } else {
#pragma unroll
        for (int j = 0; j < 8; ++j) p[j] = (_Float16)0.f;
      }
      *(half8*)&sA[arow * 40 + akq] = p;
    }
    {
      half8 u0 = *(const half8*)&w2t[(size_t)brow * 256 + k0 + bkh];
      half8 u1 = *(const half8*)&w2t[(size_t)brow * 256 + k0 + bkh + 8];
      *(half8*)&sBT[brow * 40 + bkh] = u0;
      *(half8*)&sBT[brow * 40 + bkh + 8] = u1;
    }
    __syncthreads();
    half8 af[2], bf[4];
#pragma unroll
    for (int t = 0; t < 2; ++t)
      af[t] = *(const half8*)&sA[(wm * 32 + t * 16 + (lane & 15)) * 40 + (lane >> 4) * 8];
#pragma unroll
    for (int t = 0; t < 4; ++t)
      bf[t] = *(const half8*)&sBT[(wn * 64 + t * 16 + (lane & 15)) * 40 + (lane >> 4) * 8];
#pragma unroll
    for (int tm = 0; tm < 2; ++tm)
#pragma unroll
      for (int tn = 0; tn < 4; ++tn)
        acc[tm][tn] = __builtin_amdgcn_mfma_f32_16x16x32_f16(af[tm], bf[tn], acc[tm][tn], 0, 0, 0);
    __syncthreads();
  }

  float bsv[4];
#pragma unroll
  for (int tn = 0; tn < 4; ++tn) bsv[tn] = bias[wn * 64 + tn * 16 + (lane & 15)];
  float sacc[4] = {0.f, 0.f, 0.f, 0.f}, qacc[4] = {0.f, 0.f, 0.f, 0.f};
#pragma unroll
  for (int tm = 0; tm < 2; ++tm) {
    int nbase = m0 + wm * 32 + tm * 16 + (lane >> 4) * 4;
#pragma unroll
    for (int r = 0; r < 4; ++r) {
      int n = nbase + r;
      if (n < N_NODES) {
#pragma unroll
        for (int tn = 0; tn < 4; ++tn) {
          float v = acc[tm][tn][r] + bsv[tn];
          y2[(size_t)n * 128 + wn * 64 + tn * 16 + (lane & 15)] = v;
          sacc[tn] += v; qacc[tn] += v * v;
        }
      }
    }
  }
#pragma unroll
  for (int tn = 0; tn < 4; ++tn) {
    int c = wn * 64 + tn * 16 + (lane & 15);
    atomicAdd(&ssum[c], sacc[tn]);
    atomicAdd(&ssq[c], qacc[tn]);
  }
  __syncthreads();
  if (tid < 128) {
    unsafeAtomicAdd(&gsum[tid], ssum[tid]);
    unsafeAtomicAdd(&gsq[tid], ssq[tid]);
  }
}

// ---------------- BN finalize ----------------
__global__ void k_bnfin(const float* __restrict__ sum, const float* __restrict__ sq,
                        const float* __restrict__ g, const float* __restrict__ b,
                        float* __restrict__ sc, float* __restrict__ sh, int C) {
  int c = blockIdx.x * blockDim.x + threadIdx.x;
  if (c < C) {
    const float invN = 1.0f / (float)N_NODES;
    float m = sum[c] * invN;
    float v = fmaxf(sq[c] * invN - m * m, 0.0f);
    float rs = rsqrtf(v + 1e-5f);
    float scale = g[c] * rs;
    sc[c] = scale;
    sh[c] = b[c] - m * scale;
  }
}

// ---------------- pooling: sorted-batch segment reduction with fused BN ----------------
__global__ void k_goff(const int* __restrict__ batch, int* __restrict__ goff) {
  int g = blockIdx.x * blockDim.x + threadIdx.x;
  if (g <= NG) {
    if (g == NG) { goff[g] = N_NODES; return; }
    int lo = 0, hi = N_NODES;
    while (lo < hi) { int mid = (lo + hi) >> 1; if (batch[mid] < g) lo = mid + 1; else hi = mid; }
    goff[g] = lo;
  }
}

// pooled[g][c] = sc[c] * mean(y2raw[n0:n1, c]) + sh[c]
__global__ __launch_bounds__(256) void k_poolseg(const float* __restrict__ y2raw,
                                                 const float* __restrict__ sc,
                                                 const float* __restrict__ sh,
                                                 const int* __restrict__ goff,
                                                 float* __restrict__ pooled) {
  __shared__ float sred[256];
  int g = blockIdx.x;
  int c = threadIdx.x & 127;
  int half = threadIdx.x >> 7;
  int n0 = goff[g], n1 = goff[g + 1];
  float s = 0.f;
  for (int n = n0 + half; n < n1; n += 2) s += y2raw[(size_t)n * HD + c];
  sred[threadIdx.x] = s;
  __syncthreads();
  if (threadIdx.x < 128) {
    float tot = sred[threadIdx.x] + sred[threadIdx.x + 128];
    float cntf = fmaxf((float)(n1 - n0), 1.0f);
    pooled[g * HD + threadIdx.x] = sc[threadIdx.x] * (tot / cntf) + sh[threadIdx.x];
  }
}

// ---------------- final GEMM ----------------
__global__ __launch_bounds__(128) void k_final(const float* __restrict__ pooled,
                                               const float* __restrict__ oW,
                                               const float* __restrict__ ob,
                                               float* __restrict__ out) {
  __shared__ float sP[HD];
  int g = blockIdx.x;
  int c = threadIdx.x;
  sP[c] = pooled[g * HD + c];
  __syncthreads();
  float acc = ob[c];
#pragma unroll 8
  for (int k = 0; k < HD; ++k) acc += sP[k] * oW[k * HD + c];
  out[g * HD + c] = acc;
}

extern "C" void kernel_launch(void* const* d_in, const int* in_sizes, int n_in,
                              void* d_out, int out_size, void* d_ws, size_t ws_size,
                              hipStream_t stream) {
  const int* x = (const int*)d_in[0];
  const int* ei = (const int*)d_in[1];
  const float* ea = (const float*)d_in[2];
  const int* batch = (const int*)d_in[3];
  const float* emb = (const float*)d_in[4];
  const float* eW = (const float*)d_in[5];
  const float* eb = (const float*)d_in[6];
  const float* epsA = (const float*)d_in[7];
  const float* W1 = (const float*)d_in[8];
  const float* b1 = (const float*)d_in[9];
  const float* g1 = (const float*)d_in[10];
  const float* be1 = (const float*)d_in[11];
  const float* W2 = (const float*)d_in[12];
  const float* b2 = (const float*)d_in[13];
  const float* bng = (const float*)d_in[14];
  const float* bnb = (const float*)d_in[15];
  const float* oW = (const float*)d_in[16];
  const float* ob = (const float*)d_in[17];
  float* out = (float*)d_out;

  // ----- workspace layout: ints first, then floats -----
  int* ip = (int*)d_ws;
  int* deg = ip;                         // 50,000
  int* incl = deg + 50000;               // 50,000
  int* offs = incl + 50000;              // 50,001
  int* cursor = offs + 50001;            // 50,000
  int* srcs = cursor + 50000;            // 800,000
  int* eids = srcs + 800000;             // 800,000
  int* bsum = eids + 800000;             // 200
  int* goff = bsum + 200;                // 513
  float* fp = (float*)(ip + 1800916);
  float* h = fp;                         // 6,400,000  (hbuf: raw y2 / embed output)
  float* zbuf = h + 6400000;             // 6,400,000
  _Float16* y1h = (_Float16*)(zbuf + 6400000);  // 12,800,000 halves
  float* stats = zbuf + 12800000;        // 768
  float* sc1 = stats + 768;              // 256
  float* sh1 = sc1 + 256;                // 256
  float* sc2 = sh1 + 256;                // 128
  float* sh2 = sc2 + 128;                // 128
  float* pooled = sh2 + 128;             // 65,536
  _Float16* w1t = (_Float16*)(pooled + 65536);  // 163,840 halves
  _Float16* w2t = w1t + 163840;                 // 163,840 halves
  float* ea_s = pooled + 65536 + 163840;        // 12,800,000 (optional)

  size_t needed_with = (size_t)(ea_s + 12800000 - (float*)d_ws) * 4;
  int permuted = (ws_size >= needed_with) ? 1 : 0;

  const int vec_blocks = (N_NODES * 32 + 255) / 256;
  const int edge_blocks = (N_EDGES + 255) / 256;
  const int node_blocks = (N_NODES + 255) / 256;

  k_embed<<<vec_blocks, 256, 0, stream>>>(x, emb, h);

  // CSR build + weight conversion (once per launch)
  hipMemsetAsync(deg, 0, 50000 * sizeof(int), stream);
  k_hist<<<edge_blocks, 256, 0, stream>>>(ei, deg);
  k_scan1<<<node_blocks, 256, 0, stream>>>(deg, incl, bsum);
  k_scan2<<<1, 256, 0, stream>>>(bsum, node_blocks);
  k_scan3<<<node_blocks, 256, 0, stream>>>(deg, incl, bsum, offs, cursor);
  k_scatter<<<edge_blocks, 256, 0, stream>>>(ei, ea, cursor, srcs, eids, ea_s, permuted);
  k_goff<<<3, 256, 0, stream>>>(batch, goff);
  k_cvtw1<<<640, 256, 0, stream>>>(W1, w1t);
  k_cvtw2<<<640, 256, 0, stream>>>(W2, w2t);

  for (int l = 0; l < NLAYERS; ++l) {
    hipMemsetAsync(stats, 0, 768 * sizeof(float), stream);
    // aggr consumes previous layer's raw y2 (in h) with fused BN+ReLU (identity for l=0)
    k_aggr<<<(N_NODES + 3) / 4, 256, 0, stream>>>(offs, srcs, eids, ea, ea_s,
                                                  eW + (size_t)l * EINC * HD, eb + l * HD,
                                                  epsA, l, h, sc2, sh2, (l > 0) ? 1 : 0,
                                                  zbuf, permuted);
    k_gemm1m<<<dim3(391, 2), 256, 0, stream>>>(zbuf, w1t + (size_t)l * 32768,
                                               b1 + l * 256, y1h, stats, stats + 256);
    k_bnfin<<<1, 256, 0, stream>>>(stats, stats + 256, g1 + l * 256, be1 + l * 256, sc1, sh1, 256);
    // gemm2 writes raw y2 into h (consumed by next layer's aggr or pooling)
    k_gemm2m<<<782, 256, 0, stream>>>(y1h, sc1, sh1, w2t + (size_t)l * 32768,
                                      b2 + l * HD, h, stats + 512, stats + 640);
    k_bnfin<<<1, 128, 0, stream>>>(stats + 512, stats + 640, bng + l * HD, bnb + l * HD, sc2, sh2, 128);
  }

  k_poolseg<<<NG, 256, 0, stream>>>(h, sc2, sh2, goff, pooled);
  k_final<<<NG, 128, 0, stream>>>(pooled, oW, ob, out);
}

// Round 9
// 984.419 us; speedup vs baseline: 1.2725x; 1.0878x over previous
//
#include <hip/hip_runtime.h>
#include <hip/hip_fp16.h>

#define N_NODES 50000
#define N_EDGES 800000
#define HD 128
#define NLAYERS 5
#define EINC 16
#define NG 512

typedef _Float16 half8 __attribute__((ext_vector_type(8)));
typedef _Float16 half2v __attribute__((ext_vector_type(2)));
typedef float f32x4 __attribute__((ext_vector_type(4)));
typedef float f32x2 __attribute__((ext_vector_type(2)));

// ---------------- embedding: h (fp16) = emb[x[n]] ----------------
__global__ __launch_bounds__(256) void k_embed(const int* __restrict__ x,
                                               const float* __restrict__ emb,
                                               _Float16* __restrict__ h) {
  int i = blockIdx.x * 256 + threadIdx.x;       // 8-ch groups
  if (i < N_NODES * 16) {
    int n = i >> 4, cv = i & 15;
    const float* src = &emb[(size_t)x[n] * HD + cv * 8];
    float4 a0 = *(const float4*)&src[0];
    float4 a1 = *(const float4*)&src[4];
    half8 p;
    p[0] = (_Float16)a0.x; p[1] = (_Float16)a0.y; p[2] = (_Float16)a0.z; p[3] = (_Float16)a0.w;
    p[4] = (_Float16)a1.x; p[5] = (_Float16)a1.y; p[6] = (_Float16)a1.z; p[7] = (_Float16)a1.w;
    *(half8*)&h[(size_t)n * HD + cv * 8] = p;
  }
}

// ---------------- CSR build ----------------
__global__ __launch_bounds__(256) void k_hist(const int* __restrict__ ei,
                                              int* __restrict__ deg) {
  int e = blockIdx.x * 256 + threadIdx.x;
  if (e < N_EDGES) atomicAdd(&deg[ei[N_EDGES + e]], 1);
}

__global__ __launch_bounds__(256) void k_scan1(const int* __restrict__ deg,
                                               int* __restrict__ incl,
                                               int* __restrict__ bsum) {
  __shared__ int s[256];
  int i = blockIdx.x * 256 + threadIdx.x;
  int v = (i < N_NODES) ? deg[i] : 0;
  s[threadIdx.x] = v;
  __syncthreads();
  for (int d = 1; d < 256; d <<= 1) {
    int t = (threadIdx.x >= d) ? s[threadIdx.x - d] : 0;
    __syncthreads();
    s[threadIdx.x] += t;
    __syncthreads();
  }
  if (i < N_NODES) incl[i] = s[threadIdx.x];
  if (threadIdx.x == 255) bsum[blockIdx.x] = s[255];
}

__global__ void k_scan2(int* __restrict__ bsum, int nb) {
  __shared__ int s[256];
  int v = (threadIdx.x < nb) ? bsum[threadIdx.x] : 0;
  s[threadIdx.x] = v;
  __syncthreads();
  for (int d = 1; d < 256; d <<= 1) {
    int t = (threadIdx.x >= d) ? s[threadIdx.x - d] : 0;
    __syncthreads();
    s[threadIdx.x] += t;
    __syncthreads();
  }
  if (threadIdx.x < nb) bsum[threadIdx.x] = s[threadIdx.x];
}

__global__ __launch_bounds__(256) void k_scan3(const int* __restrict__ deg,
                                               const int* __restrict__ incl,
                                               const int* __restrict__ bsum,
                                               int* __restrict__ offs,
                                               int* __restrict__ cursor) {
  int i = blockIdx.x * 256 + threadIdx.x;
  if (i < N_NODES) {
    int base = (blockIdx.x > 0) ? bsum[blockIdx.x - 1] : 0;
    int start = base + incl[i] - deg[i];
    offs[i] = start;
    cursor[i] = start;
    if (i == N_NODES - 1) offs[N_NODES] = N_EDGES;
  }
}

__global__ __launch_bounds__(256) void k_scatter(const int* __restrict__ ei,
                                                 const float* __restrict__ ea,
                                                 int* __restrict__ cursor,
                                                 int* __restrict__ srcs,
                                                 int* __restrict__ eids,
                                                 float* __restrict__ ea_s,
                                                 int permuted) {
  int e = blockIdx.x * 256 + threadIdx.x;
  if (e < N_EDGES) {
    int dst = ei[N_EDGES + e];
    int pos = atomicAdd(&cursor[dst], 1);
    srcs[pos] = ei[e];
    if (permuted) {
      float4 a0 = *(const float4*)&ea[(size_t)e * EINC];
      float4 a1 = *(const float4*)&ea[(size_t)e * EINC + 4];
      float4 a2 = *(const float4*)&ea[(size_t)e * EINC + 8];
      float4 a3 = *(const float4*)&ea[(size_t)e * EINC + 12];
      *(float4*)&ea_s[(size_t)pos * EINC] = a0;
      *(float4*)&ea_s[(size_t)pos * EINC + 4] = a1;
      *(float4*)&ea_s[(size_t)pos * EINC + 8] = a2;
      *(float4*)&ea_s[(size_t)pos * EINC + 12] = a3;
    } else {
      eids[pos] = e;
    }
  }
}

// ---------------- weight convert+transpose to fp16 (once per launch) ----------------
__global__ __launch_bounds__(256) void k_cvtw1(const float* __restrict__ W1,
                                               _Float16* __restrict__ w1t) {
  int i = blockIdx.x * 256 + threadIdx.x;
  if (i < NLAYERS * 256 * 128) {
    int l = i >> 15, r = i & 32767;
    int n = r >> 7, k = r & 127;
    w1t[i] = (_Float16)W1[(size_t)l * 32768 + k * 256 + n];
  }
}
__global__ __launch_bounds__(256) void k_cvtw2(const float* __restrict__ W2,
                                               _Float16* __restrict__ w2t) {
  int i = blockIdx.x * 256 + threadIdx.x;
  if (i < NLAYERS * 128 * 256) {
    int l = i >> 15, r = i & 32767;
    int n = r >> 8, k = r & 255;
    w2t[i] = (_Float16)W2[(size_t)l * 32768 + k * 128 + n];
  }
}

// -------- fused per-node aggregation (fp16 h in, fp16 z out) --------
// h_eff = fuse_bn ? relu(hraw*sc+sh) : hraw ;  z = (1+eps)h_eff(n) + sum_in relu(h_eff(src)+e)
__global__ __launch_bounds__(256) void k_aggr(const int* __restrict__ offs,
                                              const int* __restrict__ srcs,
                                              const int* __restrict__ eids,
                                              const float* __restrict__ ea,
                                              const float* __restrict__ ea_s,
                                              const float* __restrict__ W,   // [16][128]
                                              const float* __restrict__ eb,  // [128]
                                              const float* __restrict__ epsA, int layer,
                                              const _Float16* __restrict__ hraw,
                                              const float* __restrict__ bnsc,
                                              const float* __restrict__ bnsh,
                                              int fuse_bn,
                                              _Float16* __restrict__ z,
                                              int permuted) {
  const int wid = threadIdx.x >> 6;
  const int lane = threadIdx.x & 63;
  int n = blockIdx.x * 4 + wid;
  if (n >= N_NODES) return;
  const int c0 = lane * 2;

  f32x2 wp[EINC];
#pragma unroll
  for (int k = 0; k < EINC; ++k) wp[k] = *(const f32x2*)&W[k * HD + c0];
  const f32x2 ebp = *(const f32x2*)&eb[c0];
  const float epsv = 1.0f + epsA[layer];
  const f32x2 zero = {0.f, 0.f};
  f32x2 scp = {1.f, 1.f}, shp = {0.f, 0.f};
  if (fuse_bn) {
    scp = *(const f32x2*)&bnsc[c0];
    shp = *(const f32x2*)&bnsh[c0];
  }

  int j0 = offs[n], j1 = offs[n + 1];
  half2v hv = *(const half2v*)&hraw[(size_t)n * HD + c0];
  f32x2 hn; hn[0] = (float)hv[0]; hn[1] = (float)hv[1];
  if (fuse_bn) hn = __builtin_elementwise_max(__builtin_elementwise_fma(hn, scp, shp), zero);
  f32x2 acc;
  acc[0] = epsv * hn[0];
  acc[1] = epsv * hn[1];

  if (permuted) {
    int j = j0;
    for (; j + 3 < j1; j += 4) {
      int js = __builtin_amdgcn_readfirstlane(j);
      const float* ra = &ea_s[(size_t)js * EINC];   // 4 contiguous rows (scalar loads)
      int s0 = srcs[j], s1 = srcs[j + 1], s2 = srcs[j + 2], s3 = srcs[j + 3];
      half2v v0h = *(const half2v*)&hraw[(size_t)s0 * HD + c0];
      half2v v1h = *(const half2v*)&hraw[(size_t)s1 * HD + c0];
      half2v v2h = *(const half2v*)&hraw[(size_t)s2 * HD + c0];
      half2v v3h = *(const half2v*)&hraw[(size_t)s3 * HD + c0];
      f32x2 g0, g1, g2, g3;
      g0[0] = (float)v0h[0]; g0[1] = (float)v0h[1];
      g1[0] = (float)v1h[0]; g1[1] = (float)v1h[1];
      g2[0] = (float)v2h[0]; g2[1] = (float)v2h[1];
      g3[0] = (float)v3h[0]; g3[1] = (float)v3h[1];
      if (fuse_bn) {
        g0 = __builtin_elementwise_max(__builtin_elementwise_fma(g0, scp, shp), zero);
        g1 = __builtin_elementwise_max(__builtin_elementwise_fma(g1, scp, shp), zero);
        g2 = __builtin_elementwise_max(__builtin_elementwise_fma(g2, scp, shp), zero);
        g3 = __builtin_elementwise_max(__builtin_elementwise_fma(g3, scp, shp), zero);
      }
      f32x2 e0 = ebp, e1 = ebp, e2 = ebp, e3 = ebp;
#pragma unroll
      for (int k = 0; k < EINC; ++k) {
        f32x2 w2 = wp[k];
        float a0 = ra[k], a1 = ra[EINC + k], a2 = ra[2 * EINC + k], a3 = ra[3 * EINC + k];
        f32x2 va0 = {a0, a0}, va1 = {a1, a1}, va2 = {a2, a2}, va3 = {a3, a3};
        e0 = __builtin_elementwise_fma(va0, w2, e0);
        e1 = __builtin_elementwise_fma(va1, w2, e1);
        e2 = __builtin_elementwise_fma(va2, w2, e2);
        e3 = __builtin_elementwise_fma(va3, w2, e3);
      }
      acc += __builtin_elementwise_max(g0 + e0, zero);
      acc += __builtin_elementwise_max(g1 + e1, zero);
      acc += __builtin_elementwise_max(g2 + e2, zero);
      acc += __builtin_elementwise_max(g3 + e3, zero);
    }
    for (; j < j1; ++j) {
      int js = __builtin_amdgcn_readfirstlane(j);
      const float* ra = &ea_s[(size_t)js * EINC];
      int s0 = srcs[j];
      half2v v0h = *(const half2v*)&hraw[(size_t)s0 * HD + c0];
      f32x2 g0; g0[0] = (float)v0h[0]; g0[1] = (float)v0h[1];
      if (fuse_bn) g0 = __builtin_elementwise_max(__builtin_elementwise_fma(g0, scp, shp), zero);
      f32x2 e0 = ebp;
#pragma unroll
      for (int k = 0; k < EINC; ++k) {
        float a0 = ra[k];
        f32x2 va0 = {a0, a0};
        e0 = __builtin_elementwise_fma(va0, wp[k], e0);
      }
      acc += __builtin_elementwise_max(g0 + e0, zero);
    }
  } else {
    for (int j = j0; j < j1; ++j) {
      int eid = __builtin_amdgcn_readfirstlane(eids[j]);
      const float* ra = &ea[(size_t)eid * EINC];
      int s0 = srcs[j];
      half2v v0h = *(const half2v*)&hraw[(size_t)s0 * HD + c0];
      f32x2 g0; g0[0] = (float)v0h[0]; g0[1] = (float)v0h[1];
      if (fuse_bn) g0 = __builtin_elementwise_max(__builtin_elementwise_fma(g0, scp, shp), zero);
      f32x2 e0 = ebp;
#pragma unroll
      for (int k = 0; k < EINC; ++k) {
        float a0 = ra[k];
        f32x2 va0 = {a0, a0};
        e0 = __builtin_elementwise_fma(va0, wp[k], e0);
      }
      acc += __builtin_elementwise_max(g0 + e0, zero);
    }
  }
  half2v oz; oz[0] = (_Float16)acc[0]; oz[1] = (_Float16)acc[1];
  *(half2v*)&z[(size_t)n * HD + c0] = oz;
}

// ---------- GEMM1 (MFMA fp16): y1h = fp16(z @ W1 + b1) ; col stats ----------
__global__ __launch_bounds__(256) void k_gemm1m(const _Float16* __restrict__ z,
                                                const _Float16* __restrict__ w1t, // [256][128]
                                                const float* __restrict__ bias,   // [256]
                                                _Float16* __restrict__ y1h,
                                                float* __restrict__ gsum,
                                                float* __restrict__ gsq) {
  __shared__ _Float16 sA[128 * 40];
  __shared__ _Float16 sBT[128 * 40];
  __shared__ float ssum[128], ssq[128];
  const int tid = threadIdx.x;
  const int lane = tid & 63;
  const int wid = tid >> 6;
  const int wm = wid >> 1, wn = wid & 1;
  const int m0 = blockIdx.x * 128;
  const int n0 = blockIdx.y * 128;

  if (tid < 128) { ssum[tid] = 0.f; ssq[tid] = 0.f; }

  f32x4 acc[4][4];
  const f32x4 zz = {0.f, 0.f, 0.f, 0.f};
#pragma unroll
  for (int a = 0; a < 4; ++a)
#pragma unroll
    for (int b = 0; b < 4; ++b) acc[a][b] = zz;

  const int srow = tid >> 1;
  const int skh = (tid & 1) * 16;

  for (int k0 = 0; k0 < 128; k0 += 32) {
    {
      int n = m0 + srow;
      half8 p0, p1;
      if (n < N_NODES) {
        p0 = *(const half8*)&z[(size_t)n * 128 + k0 + skh];
        p1 = *(const half8*)&z[(size_t)n * 128 + k0 + skh + 8];
      } else {
#pragma unroll
        for (int j = 0; j < 8; ++j) { p0[j] = (_Float16)0.f; p1[j] = (_Float16)0.f; }
      }
      *(half8*)&sA[srow * 40 + skh] = p0;
      *(half8*)&sA[srow * 40 + skh + 8] = p1;
    }
    {
      half8 u0 = *(const half8*)&w1t[(size_t)(n0 + srow) * 128 + k0 + skh];
      half8 u1 = *(const half8*)&w1t[(size_t)(n0 + srow) * 128 + k0 + skh + 8];
      *(half8*)&sBT[srow * 40 + skh] = u0;
      *(half8*)&sBT[srow * 40 + skh + 8] = u1;
    }
    __syncthreads();
    half8 af[4], bf[4];
#pragma unroll
    for (int t = 0; t < 4; ++t) {
      af[t] = *(const half8*)&sA[(wm * 64 + t * 16 + (lane & 15)) * 40 + (lane >> 4) * 8];
      bf[t] = *(const half8*)&sBT[(wn * 64 + t * 16 + (lane & 15)) * 40 + (lane >> 4) * 8];
    }
#pragma unroll
    for (int tm = 0; tm < 4; ++tm)
#pragma unroll
      for (int tn = 0; tn < 4; ++tn)
        acc[tm][tn] = __builtin_amdgcn_mfma_f32_16x16x32_f16(af[tm], bf[tn], acc[tm][tn], 0, 0, 0);
    __syncthreads();
  }

  float bsv[4];
#pragma unroll
  for (int tn = 0; tn < 4; ++tn) bsv[tn] = bias[n0 + wn * 64 + tn * 16 + (lane & 15)];
  float sacc[4] = {0.f, 0.f, 0.f, 0.f}, qacc[4] = {0.f, 0.f, 0.f, 0.f};
#pragma unroll
  for (int tm = 0; tm < 4; ++tm) {
    int nbase = m0 + wm * 64 + tm * 16 + (lane >> 4) * 4;
#pragma unroll
    for (int r = 0; r < 4; ++r) {
      int n = nbase + r;
      if (n < N_NODES) {
#pragma unroll
        for (int tn = 0; tn < 4; ++tn) {
          float v = acc[tm][tn][r] + bsv[tn];
          y1h[(size_t)n * 256 + n0 + wn * 64 + tn * 16 + (lane & 15)] = (_Float16)v;
          sacc[tn] += v; qacc[tn] += v * v;
        }
      }
    }
  }
#pragma unroll
  for (int tn = 0; tn < 4; ++tn) {
    int c = wn * 64 + tn * 16 + (lane & 15);
    atomicAdd(&ssum[c], sacc[tn]);
    atomicAdd(&ssq[c], qacc[tn]);
  }
  __syncthreads();
  if (tid < 128) {
    unsafeAtomicAdd(&gsum[n0 + tid], ssum[tid]);
    unsafeAtomicAdd(&gsq[n0 + tid], ssq[tid]);
  }
}

// ---------- GEMM2 (MFMA fp16): hraw(fp16) = y1bn @ W2 + b2 ; col stats ----------
__global__ __launch_bounds__(256) void k_gemm2m(const _Float16* __restrict__ y1h,
                                                const float* __restrict__ sc,
                                                const float* __restrict__ sh,
                                                const _Float16* __restrict__ w2t, // [128][256]
                                                const float* __restrict__ bias,   // [128]
                                                _Float16* __restrict__ y2,
                                                float* __restrict__ gsum,
                                                float* __restrict__ gsq) {
  __shared__ _Float16 sA[64 * 40];
  __shared__ _Float16 sBT[128 * 40];
  __shared__ float ssc[256], ssh[256];
  __shared__ float ssum[128], ssq[128];
  const int tid = threadIdx.x;
  const int lane = tid & 63;
  const int wid = tid >> 6;
  const int wm = wid >> 1, wn = wid & 1;
  const int m0 = blockIdx.x * 64;

  ssc[tid] = sc[tid];
  ssh[tid] = sh[tid];
  if (tid < 128) { ssum[tid] = 0.f; ssq[tid] = 0.f; }
  __syncthreads();

  f32x4 acc[2][4];
  const f32x4 zz = {0.f, 0.f, 0.f, 0.f};
#pragma unroll
  for (int a = 0; a < 2; ++a)
#pragma unroll
    for (int b = 0; b < 4; ++b) acc[a][b] = zz;

  const int arow = tid >> 2;
  const int akq = (tid & 3) * 8;
  const int brow = tid >> 1;
  const int bkh = (tid & 1) * 16;

  for (int k0 = 0; k0 < 256; k0 += 32) {
    {
      int n = m0 + arow;
      half8 p;
      if (n < N_NODES) {
        half8 yv = *(const half8*)&y1h[(size_t)n * 256 + k0 + akq];
#pragma unroll
        for (int j = 0; j < 8; ++j) {
          float v = fmaxf((float)yv[j] * ssc[k0 + akq + j] + ssh[k0 + akq + j], 0.f);
          p[j] = (_Float16)v;
        }
      } else {
#pragma unroll
        for (int j = 0; j < 8; ++j) p[j] = (_Float16)0.f;
      }
      *(half8*)&sA[arow * 40 + akq] = p;
    }
    {
      half8 u0 = *(const half8*)&w2t[(size_t)brow * 256 + k0 + bkh];
      half8 u1 = *(const half8*)&w2t[(size_t)brow * 256 + k0 + bkh + 8];
      *(half8*)&sBT[brow * 40 + bkh] = u0;
      *(half8*)&sBT[brow * 40 + bkh + 8] = u1;
    }
    __syncthreads();
    half8 af[2], bf[4];
#pragma unroll
    for (int t = 0; t < 2; ++t)
      af[t] = *(const half8*)&sA[(wm * 32 + t * 16 + (lane & 15)) * 40 + (lane >> 4) * 8];
#pragma unroll
    for (int t = 0; t < 4; ++t)
      bf[t] = *(const half8*)&sBT[(wn * 64 + t * 16 + (lane & 15)) * 40 + (lane >> 4) * 8];
#pragma unroll
    for (int tm = 0; tm < 2; ++tm)
#pragma unroll
      for (int tn = 0; tn < 4; ++tn)
        acc[tm][tn] = __builtin_amdgcn_mfma_f32_16x16x32_f16(af[tm], bf[tn], acc[tm][tn], 0, 0, 0);
    __syncthreads();
  }

  float bsv[4];
#pragma unroll
  for (int tn = 0; tn < 4; ++tn) bsv[tn] = bias[wn * 64 + tn * 16 + (lane & 15)];
  float sacc[4] = {0.f, 0.f, 0.f, 0.f}, qacc[4] = {0.f, 0.f, 0.f, 0.f};
#pragma unroll
  for (int tm = 0; tm < 2; ++tm) {
    int nbase = m0 + wm * 32 + tm * 16 + (lane >> 4) * 4;
#pragma unroll
    for (int r = 0; r < 4; ++r) {
      int n = nbase + r;
      if (n < N_NODES) {
#pragma unroll
        for (int tn = 0; tn < 4; ++tn) {
          float v = acc[tm][tn][r] + bsv[tn];
          y2[(size_t)n * 128 + wn * 64 + tn * 16 + (lane & 15)] = (_Float16)v;
          sacc[tn] += v; qacc[tn] += v * v;
        }
      }
    }
  }
#pragma unroll
  for (int tn = 0; tn < 4; ++tn) {
    int c = wn * 64 + tn * 16 + (lane & 15);
    atomicAdd(&ssum[c], sacc[tn]);
    atomicAdd(&ssq[c], qacc[tn]);
  }
  __syncthreads();
  if (tid < 128) {
    unsafeAtomicAdd(&gsum[tid], ssum[tid]);
    unsafeAtomicAdd(&gsq[tid], ssq[tid]);
  }
}

// ---------------- BN finalize ----------------
__global__ void k_bnfin(const float* __restrict__ sum, const float* __restrict__ sq,
                        const float* __restrict__ g, const float* __restrict__ b,
                        float* __restrict__ sc, float* __restrict__ sh, int C) {
  int c = blockIdx.x * blockDim.x + threadIdx.x;
  if (c < C) {
    const float invN = 1.0f / (float)N_NODES;
    float m = sum[c] * invN;
    float v = fmaxf(sq[c] * invN - m * m, 0.0f);
    float rs = rsqrtf(v + 1e-5f);
    float scale = g[c] * rs;
    sc[c] = scale;
    sh[c] = b[c] - m * scale;
  }
}

// ---------------- pooling: sorted-batch segment reduction with fused BN ----------------
__global__ void k_goff(const int* __restrict__ batch, int* __restrict__ goff) {
  int g = blockIdx.x * blockDim.x + threadIdx.x;
  if (g <= NG) {
    if (g == NG) { goff[g] = N_NODES; return; }
    int lo = 0, hi = N_NODES;
    while (lo < hi) { int mid = (lo + hi) >> 1; if (batch[mid] < g) lo = mid + 1; else hi = mid; }
    goff[g] = lo;
  }
}

// pooled[g][c] = sc[c] * mean(y2raw[n0:n1, c]) + sh[c]   (y2raw fp16)
__global__ __launch_bounds__(256) void k_poolseg(const _Float16* __restrict__ y2raw,
                                                 const float* __restrict__ sc,
                                                 const float* __restrict__ sh,
                                                 const int* __restrict__ goff,
                                                 float* __restrict__ pooled) {
  __shared__ float sred[256];
  int g = blockIdx.x;
  int c = threadIdx.x & 127;
  int half = threadIdx.x >> 7;
  int n0 = goff[g], n1 = goff[g + 1];
  float s = 0.f;
  for (int n = n0 + half; n < n1; n += 2) s += (float)y2raw[(size_t)n * HD + c];
  sred[threadIdx.x] = s;
  __syncthreads();
  if (threadIdx.x < 128) {
    float tot = sred[threadIdx.x] + sred[threadIdx.x + 128];
    float cntf = fmaxf((float)(n1 - n0), 1.0f);
    pooled[g * HD + threadIdx.x] = sc[threadIdx.x] * (tot / cntf) + sh[threadIdx.x];
  }
}

// ---------------- final GEMM ----------------
__global__ __launch_bounds__(128) void k_final(const float* __restrict__ pooled,
                                               const float* __restrict__ oW,
                                               const float* __restrict__ ob,
                                               float* __restrict__ out) {
  __shared__ float sP[HD];
  int g = blockIdx.x;
  int c = threadIdx.x;
  sP[c] = pooled[g * HD + c];
  __syncthreads();
  float acc = ob[c];
#pragma unroll 8
  for (int k = 0; k < HD; ++k) acc += sP[k] * oW[k * HD + c];
  out[g * HD + c] = acc;
}

extern "C" void kernel_launch(void* const* d_in, const int* in_sizes, int n_in,
                              void* d_out, int out_size, void* d_ws, size_t ws_size,
                              hipStream_t stream) {
  const int* x = (const int*)d_in[0];
  const int* ei = (const int*)d_in[1];
  const float* ea = (const float*)d_in[2];
  const int* batch = (const int*)d_in[3];
  const float* emb = (const float*)d_in[4];
  const float* eW = (const float*)d_in[5];
  const float* eb = (const float*)d_in[6];
  const float* epsA = (const float*)d_in[7];
  const float* W1 = (const float*)d_in[8];
  const float* b1 = (const float*)d_in[9];
  const float* g1 = (const float*)d_in[10];
  const float* be1 = (const float*)d_in[11];
  const float* W2 = (const float*)d_in[12];
  const float* b2 = (const float*)d_in[13];
  const float* bng = (const float*)d_in[14];
  const float* bnb = (const float*)d_in[15];
  const float* oW = (const float*)d_in[16];
  const float* ob = (const float*)d_in[17];
  float* out = (float*)d_out;

  // ----- workspace layout: ints first, then floats -----
  int* ip = (int*)d_ws;
  int* deg = ip;                         // 50,000
  int* incl = deg + 50000;               // 50,000
  int* offs = incl + 50000;              // 50,001
  int* cursor = offs + 50001;            // 50,000
  int* srcs = cursor + 50000;            // 800,000
  int* eids = srcs + 800000;             // 800,000
  int* bsum = eids + 800000;             // 200
  int* goff = bsum + 200;                // 513
  float* fp = (float*)(ip + 1800916);
  _Float16* h = (_Float16*)fp;                  // fp16, region sized 6,400,000 floats
  _Float16* zbuf = (_Float16*)(fp + 6400000);   // fp16
  _Float16* y1h = (_Float16*)(fp + 12800000);   // 12,800,000 halves
  float* stats = fp + 19200000;          // 768
  float* sc1 = stats + 768;              // 256
  float* sh1 = sc1 + 256;                // 256
  float* sc2 = sh1 + 256;                // 128
  float* sh2 = sc2 + 128;                // 128
  float* pooled = sh2 + 128;             // 65,536
  _Float16* w1t = (_Float16*)(pooled + 65536);  // 163,840 halves
  _Float16* w2t = w1t + 163840;                 // 163,840 halves
  float* ea_s = pooled + 65536 + 163840;        // 12,800,000 (optional)

  size_t needed_with = (size_t)(ea_s + 12800000 - (float*)d_ws) * 4;
  int permuted = (ws_size >= needed_with) ? 1 : 0;

  const int edge_blocks = (N_EDGES + 255) / 256;
  const int node_blocks = (N_NODES + 255) / 256;

  k_embed<<<(N_NODES * 16 + 255) / 256, 256, 0, stream>>>(x, emb, h);

  // CSR build + weight conversion (once per launch)
  hipMemsetAsync(deg, 0, 50000 * sizeof(int), stream);
  k_hist<<<edge_blocks, 256, 0, stream>>>(ei, deg);
  k_scan1<<<node_blocks, 256, 0, stream>>>(deg, incl, bsum);
  k_scan2<<<1, 256, 0, stream>>>(bsum, node_blocks);
  k_scan3<<<node_blocks, 256, 0, stream>>>(deg, incl, bsum, offs, cursor);
  k_scatter<<<edge_blocks, 256, 0, stream>>>(ei, ea, cursor, srcs, eids, ea_s, permuted);
  k_goff<<<3, 256, 0, stream>>>(batch, goff);
  k_cvtw1<<<640, 256, 0, stream>>>(W1, w1t);
  k_cvtw2<<<640, 256, 0, stream>>>(W2, w2t);

  for (int l = 0; l < NLAYERS; ++l) {
    hipMemsetAsync(stats, 0, 768 * sizeof(float), stream);
    // aggr consumes previous layer's raw y2 (fp16, in h) with fused BN+ReLU (identity for l=0)
    k_aggr<<<(N_NODES + 3) / 4, 256, 0, stream>>>(offs, srcs, eids, ea, ea_s,
                                                  eW + (size_t)l * EINC * HD, eb + l * HD,
                                                  epsA, l, h, sc2, sh2, (l > 0) ? 1 : 0,
                                                  zbuf, permuted);
    k_gemm1m<<<dim3(391, 2), 256, 0, stream>>>(zbuf, w1t + (size_t)l * 32768,
                                               b1 + l * 256, y1h, stats, stats + 256);
    k_bnfin<<<1, 256, 0, stream>>>(stats, stats + 256, g1 + l * 256, be1 + l * 256, sc1, sh1, 256);
    // gemm2 writes raw y2 (fp16) into h (consumed by next layer's aggr or pooling)
    k_gemm2m<<<782, 256, 0, stream>>>(y1h, sc1, sh1, w2t + (size_t)l * 32768,
                                      b2 + l * HD, h, stats + 512, stats + 640);
    k_bnfin<<<1, 128, 0, stream>>>(stats + 512, stats + 640, bng + l * HD, bnb + l * HD, sc2, sh2, 128);
  }

  k_poolseg<<<NG, 256, 0, stream>>>(h, sc2, sh2, goff, pooled);
  k_final<<<NG, 128, 0, stream>>>(pooled, oW, ob, out);
}